// Round 9
// baseline (476.263 us; speedup 1.0000x reference)
//
#include <hip/hip_runtime.h>

#define N_NODES 100000
#define N_EDGES 1600000
#define N_GRAPHS_C 64
#define IN_F 86
#define H 64
#define N_BKT 391            // ceil(100000/256), bucket = dst >> 8
#define SC_EPT 8             // edges per thread in bucket passes
#define SC_TILE 2048         // 256 threads * 8
#define SC_GRID 782          // ceil(1.6M / 2048)
#define BC_GRID 3440         // bn+count grid: 3440*256 = 880640, divisible by 86
#define NW_POOL 2048         // waves in pool_k
typedef unsigned short ushort;

__device__ inline float bf2f(ushort u) { return __uint_as_float(((unsigned)u) << 16); }
__device__ inline ushort f2bf(float f) {
    unsigned x = __float_as_uint(f);
    return (ushort)((x + 0x7fffu + ((x >> 16) & 1u)) >> 16);  // RNE
}

// ---------------- fused: BN stats + per-bucket edge counts ----------------
__global__ void bn_count_k(const float* __restrict__ x, const int* __restrict__ dst,
                           float* __restrict__ bnsum, float* __restrict__ bnsq,
                           int* __restrict__ bcnt) {
    __shared__ float s1[IN_F], s2[IN_F];
    __shared__ int hist[N_BKT];
    int tid = threadIdx.x;
    if (tid < IN_F) { s1[tid] = 0.f; s2[tid] = 0.f; }
    for (int i = tid; i < N_BKT; i += 256) hist[i] = 0;
    __syncthreads();
    if (blockIdx.x < SC_GRID) {
        int e0 = blockIdx.x * SC_TILE;
#pragma unroll
        for (int i = 0; i < SC_EPT; i++) {
            int e = e0 + i * 256 + tid;
            if (e < N_EDGES) atomicAdd(&hist[dst[e] >> 8], 1);
        }
    }
    const int T = BC_GRID * 256;
    int t = blockIdx.x * 256 + tid;
    float sum = 0.f, sq = 0.f;
#pragma unroll 4
    for (int idx = t; idx < N_NODES * IN_F; idx += T) {
        float v = x[idx];
        sum += v; sq += v * v;
    }
    int f = t % IN_F;
    atomicAdd(&s1[f], sum);
    atomicAdd(&s2[f], sq);
    __syncthreads();
    if (tid < IN_F) {
        atomicAdd(&bnsum[tid], s1[tid]);
        atomicAdd(&bnsq[tid], s2[tid]);
    }
    if (blockIdx.x < SC_GRID)
        for (int i = tid; i < N_BKT; i += 256) atomicAdd(&bcnt[i], hist[i]);
}

// ---------------- fused: bucket scan + BN-fold prep ----------------
__global__ void scanprep_k(const int* __restrict__ bcnt, int* __restrict__ bstart,
                           int* __restrict__ gcursor,
                           const float* __restrict__ bnsum, const float* __restrict__ bnsq,
                           const float* __restrict__ gamma, const float* __restrict__ beta,
                           const float* __restrict__ W1, const float* __restrict__ b1,
                           float* __restrict__ W1p, float* __restrict__ c1) {
    __shared__ int tmp[512];
    __shared__ float scale[IN_F], shift[IN_F];
    int t = threadIdx.x;
    int v = (t < N_BKT) ? bcnt[t] : 0;
    tmp[t] = v;
    __syncthreads();
    for (int off = 1; off < 512; off <<= 1) {
        int a = (t >= off) ? tmp[t - off] : 0;
        __syncthreads();
        tmp[t] += a;
        __syncthreads();
    }
    if (t < N_BKT) { bstart[t] = tmp[t] - v; gcursor[t] = tmp[t] - v; }
    if (t == N_BKT - 1) bstart[N_BKT] = tmp[t];
    if (t < IN_F) {
        float mean = bnsum[t] * (1.0f / N_NODES);
        float var  = bnsq[t] * (1.0f / N_NODES) - mean * mean;
        float sc = gamma[t] * rsqrtf(var + 1e-5f);
        scale[t] = sc;
        shift[t] = beta[t] - mean * sc;
    }
    __syncthreads();
    for (int idx = t; idx < IN_F * H; idx += 512) W1p[idx] = scale[idx / H] * W1[idx];
    if (t < H) {
        float acc = b1[t];
        for (int i = 0; i < IN_F; i++) acc += shift[i] * W1[i * H + t];
        c1[t] = acc;
    }
}

// ---------------- CSR pass 1: partition edges (packed (src<<8)|dstLow) ----------------
__global__ void bucket_scatter_k(const int* __restrict__ src, const int* __restrict__ dst,
                                 int* __restrict__ gcursor, unsigned* __restrict__ ebkt) {
    __shared__ int hist[N_BKT];
    __shared__ int base[N_BKT];
    int tid = threadIdx.x;
    for (int i = tid; i < N_BKT; i += 256) hist[i] = 0;
    __syncthreads();
    int e0 = blockIdx.x * SC_TILE;
    unsigned pk[SC_EPT];
    int bk[SC_EPT], lo[SC_EPT];
#pragma unroll
    for (int i = 0; i < SC_EPT; i++) {
        int e = e0 + i * 256 + tid;
        if (e < N_EDGES) {
            int d = dst[e];
            pk[i] = ((unsigned)src[e] << 8) | (unsigned)(d & 255);
            bk[i] = d >> 8;
            lo[i] = atomicAdd(&hist[bk[i]], 1);
        }
    }
    __syncthreads();
    for (int i = tid; i < N_BKT; i += 256) base[i] = atomicAdd(&gcursor[i], hist[i]);
    __syncthreads();
#pragma unroll
    for (int i = 0; i < SC_EPT; i++) {
        int e = e0 + i * 256 + tid;
        if (e < N_EDGES) ebkt[base[bk[i]] + lo[i]] = pk[i];
    }
}

// ---------------- CSR pass 2: per-bucket degree+scan+fill ----------------
// rs[n] = INCLUSIVE end of node n's csr row. csr entries are BYTE offsets (src*128).
__global__ void bucket_fill_k(const unsigned* __restrict__ ebkt, const int* __restrict__ bstart,
                              int* __restrict__ rs, int* __restrict__ csr) {
    __shared__ int deg[256];
    __shared__ int scn[256];
    __shared__ int cur[256];
    int b = blockIdx.x;
    int tid = threadIdx.x;
    int e0 = bstart[b], e1 = bstart[b + 1];
    deg[tid] = 0;
    __syncthreads();
    for (int e = e0 + tid; e < e1; e += 256) atomicAdd(&deg[ebkt[e] & 255u], 1);
    __syncthreads();
    scn[tid] = deg[tid];
    __syncthreads();
    for (int off = 1; off < 256; off <<= 1) {
        int a = (tid >= off) ? scn[tid - off] : 0;
        __syncthreads();
        scn[tid] += a;
        __syncthreads();
    }
    int node = (b << 8) + tid;
    if (node < N_NODES) rs[node] = e0 + scn[tid];
    cur[tid] = e0 + scn[tid] - deg[tid];
    __syncthreads();
    for (int e = e0 + tid; e < e1; e += 256) {
        unsigned p = ebkt[e];
        int pos = atomicAdd(&cur[p & 255u], 1);
        csr[pos] = (int)((p & ~255u) >> 1);   // src*128 byte offset
    }
}

// ---------------- GEMM (f32 in, K=86): Ybf16 = X @ W + bias ----------------
__global__ __launch_bounds__(256) void gemm_f32_k(const float* __restrict__ X,
                                                  const float* __restrict__ W,
                                                  const float* __restrict__ bias,
                                                  ushort* __restrict__ Y, int N) {
    const int K = IN_F;
    __shared__ __align__(16) float Xl[64][IN_F + 1];
    __shared__ __align__(16) float Wl[IN_F][64];
    int tid = threadIdx.x;
    int row0 = blockIdx.x * 64;
    for (int i = tid; i < K * 64; i += 256) Wl[i / 64][i % 64] = W[i];
    for (int i = tid; i < 64 * K; i += 256) {
        int r = i / K, c = i % K;
        Xl[r][c] = (row0 + r < N) ? X[(size_t)(row0 + r) * K + c] : 0.f;
    }
    __syncthreads();
    int cg = tid & 15, rg = tid >> 4;
    float4 b4 = *(const float4*)&bias[cg * 4];
    float acc[4][4];
    for (int i = 0; i < 4; i++) { acc[i][0] = b4.x; acc[i][1] = b4.y; acc[i][2] = b4.z; acc[i][3] = b4.w; }
    for (int k = 0; k < K; k++) {
        float4 w = *(const float4*)&Wl[k][cg * 4];
        float x0 = Xl[rg * 4 + 0][k];
        float x1 = Xl[rg * 4 + 1][k];
        float x2 = Xl[rg * 4 + 2][k];
        float x3 = Xl[rg * 4 + 3][k];
        acc[0][0] += x0 * w.x; acc[0][1] += x0 * w.y; acc[0][2] += x0 * w.z; acc[0][3] += x0 * w.w;
        acc[1][0] += x1 * w.x; acc[1][1] += x1 * w.y; acc[1][2] += x1 * w.z; acc[1][3] += x1 * w.w;
        acc[2][0] += x2 * w.x; acc[2][1] += x2 * w.y; acc[2][2] += x2 * w.z; acc[2][3] += x2 * w.w;
        acc[3][0] += x3 * w.x; acc[3][1] += x3 * w.y; acc[3][2] += x3 * w.z; acc[3][3] += x3 * w.w;
    }
    for (int i = 0; i < 4; i++) {
        int gr = row0 + rg * 4 + i;
        if (gr < N) {
            ushort4 o;
            o.x = f2bf(acc[i][0]); o.y = f2bf(acc[i][1]);
            o.z = f2bf(acc[i][2]); o.w = f2bf(acc[i][3]);
            *(ushort4*)&Y[(size_t)gr * 64 + cg * 4] = o;
        }
    }
}

// ---------------- GEMM (bf16 in, K=64): Ybf16 = X @ W + bias ----------------
__global__ __launch_bounds__(256) void gemm_bf16_k(const ushort* __restrict__ X,
                                                   const float* __restrict__ W,
                                                   const float* __restrict__ bias,
                                                   ushort* __restrict__ Y, int N) {
    const int K = H;
    __shared__ __align__(16) float Xl[64][H + 1];
    __shared__ __align__(16) float Wl[H][64];
    int tid = threadIdx.x;
    int row0 = blockIdx.x * 64;
    for (int i = tid; i < K * 64; i += 256) Wl[i / 64][i % 64] = W[i];
    for (int i = tid; i < 64 * 16; i += 256) {
        int r = i >> 4, c4 = (i & 15) * 4;
        if (row0 + r < N) {
            ushort4 u = *(const ushort4*)&X[(size_t)(row0 + r) * K + c4];
            Xl[r][c4 + 0] = bf2f(u.x); Xl[r][c4 + 1] = bf2f(u.y);
            Xl[r][c4 + 2] = bf2f(u.z); Xl[r][c4 + 3] = bf2f(u.w);
        } else {
            Xl[r][c4 + 0] = 0.f; Xl[r][c4 + 1] = 0.f;
            Xl[r][c4 + 2] = 0.f; Xl[r][c4 + 3] = 0.f;
        }
    }
    __syncthreads();
    int cg = tid & 15, rg = tid >> 4;
    float4 b4 = *(const float4*)&bias[cg * 4];
    float acc[4][4];
    for (int i = 0; i < 4; i++) { acc[i][0] = b4.x; acc[i][1] = b4.y; acc[i][2] = b4.z; acc[i][3] = b4.w; }
    for (int k = 0; k < K; k++) {
        float4 w = *(const float4*)&Wl[k][cg * 4];
        float x0 = Xl[rg * 4 + 0][k];
        float x1 = Xl[rg * 4 + 1][k];
        float x2 = Xl[rg * 4 + 2][k];
        float x3 = Xl[rg * 4 + 3][k];
        acc[0][0] += x0 * w.x; acc[0][1] += x0 * w.y; acc[0][2] += x0 * w.z; acc[0][3] += x0 * w.w;
        acc[1][0] += x1 * w.x; acc[1][1] += x1 * w.y; acc[1][2] += x1 * w.z; acc[1][3] += x1 * w.w;
        acc[2][0] += x2 * w.x; acc[2][1] += x2 * w.y; acc[2][2] += x2 * w.z; acc[2][3] += x2 * w.w;
        acc[3][0] += x3 * w.x; acc[3][1] += x3 * w.y; acc[3][2] += x3 * w.z; acc[3][3] += x3 * w.w;
    }
    for (int i = 0; i < 4; i++) {
        int gr = row0 + rg * 4 + i;
        if (gr < N) {
            ushort4 o;
            o.x = f2bf(acc[i][0]); o.y = f2bf(acc[i][1]);
            o.z = f2bf(acc[i][2]); o.w = f2bf(acc[i][3]);
            *(ushort4*)&Y[(size_t)gr * 64 + cg * 4] = o;
        }
    }
}

// ---------------- gather core: half-wave paired rows, uint loads ----------------
// Lanes 0-31 process even neighbor slots, lanes 32-63 odd slots; each lane
// loads 4B = feats {2*fl, 2*fl+1}. Final __shfl_xor(32) combines halves.
__device__ inline void gather_row2(const char* __restrict__ gB, const int* __restrict__ csr,
                                   int start, int end, int lane, float& olo, float& ohi) {
    int half = lane >> 5;
    int fl = lane & 31;
    const char* gL = gB + (fl << 2);
    float lo0 = 0.f, lo1 = 0.f, lo2 = 0.f, lo3 = 0.f;
    float lo4 = 0.f, lo5 = 0.f, lo6 = 0.f, lo7 = 0.f;
    float hi0 = 0.f, hi1 = 0.f, hi2 = 0.f, hi3 = 0.f;
    float hi4 = 0.f, hi5 = 0.f, hi6 = 0.f, hi7 = 0.f;
    for (int j0 = start; j0 < end; j0 += 64) {
        int cnt = min(64, end - j0);
        int myoff = (lane < cnt) ? csr[j0 + lane] : 0;
        int j = 0;
        for (; j + 16 <= cnt; j += 16) {
            int s0 = __shfl(myoff, j + 0 + half, 64);
            int s1 = __shfl(myoff, j + 2 + half, 64);
            int s2 = __shfl(myoff, j + 4 + half, 64);
            int s3 = __shfl(myoff, j + 6 + half, 64);
            int s4 = __shfl(myoff, j + 8 + half, 64);
            int s5 = __shfl(myoff, j + 10 + half, 64);
            int s6 = __shfl(myoff, j + 12 + half, 64);
            int s7 = __shfl(myoff, j + 14 + half, 64);
            unsigned u0 = *(const unsigned*)(gL + s0);
            unsigned u1 = *(const unsigned*)(gL + s1);
            unsigned u2 = *(const unsigned*)(gL + s2);
            unsigned u3 = *(const unsigned*)(gL + s3);
            unsigned u4 = *(const unsigned*)(gL + s4);
            unsigned u5 = *(const unsigned*)(gL + s5);
            unsigned u6 = *(const unsigned*)(gL + s6);
            unsigned u7 = *(const unsigned*)(gL + s7);
            lo0 += __uint_as_float(u0 << 16); hi0 += __uint_as_float(u0 & 0xffff0000u);
            lo1 += __uint_as_float(u1 << 16); hi1 += __uint_as_float(u1 & 0xffff0000u);
            lo2 += __uint_as_float(u2 << 16); hi2 += __uint_as_float(u2 & 0xffff0000u);
            lo3 += __uint_as_float(u3 << 16); hi3 += __uint_as_float(u3 & 0xffff0000u);
            lo4 += __uint_as_float(u4 << 16); hi4 += __uint_as_float(u4 & 0xffff0000u);
            lo5 += __uint_as_float(u5 << 16); hi5 += __uint_as_float(u5 & 0xffff0000u);
            lo6 += __uint_as_float(u6 << 16); hi6 += __uint_as_float(u6 & 0xffff0000u);
            lo7 += __uint_as_float(u7 << 16); hi7 += __uint_as_float(u7 & 0xffff0000u);
        }
        for (; j < cnt; j += 2) {
            int idx = j + half;
            int s = __shfl(myoff, (idx < cnt) ? idx : (cnt - 1), 64);
            unsigned u = *(const unsigned*)(gL + s);
            if (idx < cnt) {
                lo0 += __uint_as_float(u << 16);
                hi0 += __uint_as_float(u & 0xffff0000u);
            }
        }
    }
    float lo = ((lo0 + lo1) + (lo2 + lo3)) + ((lo4 + lo5) + (lo6 + lo7));
    float hi = ((hi0 + hi1) + (hi2 + hi3)) + ((hi4 + hi5) + (hi6 + hi7));
    lo += __shfl_xor(lo, 32, 64);
    hi += __shfl_xor(hi, 32, 64);
    olo = lo; ohi = hi;
}

// ---------------- gather: h[n] = relu(mean in-nbr g or g[n]) -> bf16 ----------------
__global__ void gather_k(const ushort* __restrict__ g, const int* __restrict__ rs,
                         const int* __restrict__ csr, ushort* __restrict__ out) {
    int lane = threadIdx.x & 63;
    int n = blockIdx.x * 4 + (threadIdx.x >> 6);
    if (n >= N_NODES) return;
    int start = (n == 0) ? 0 : rs[n - 1];
    int end = rs[n];
    float lo, hi;
    gather_row2((const char*)g, csr, start, end, lane, lo, hi);
    int d = end - start;
    int fl = lane & 31;
    float vlo, vhi;
    if (d > 0) {
        float inv = 1.0f / (float)d;
        vlo = lo * inv; vhi = hi * inv;
    } else {
        unsigned u = *(const unsigned*)((const char*)g + (size_t)n * 128 + (fl << 2));
        vlo = __uint_as_float(u << 16);
        vhi = __uint_as_float(u & 0xffff0000u);
    }
    vlo = fmaxf(vlo, 0.f); vhi = fmaxf(vhi, 0.f);
    if (lane < 32) {
        ushort2 o; o.x = f2bf(vlo); o.y = f2bf(vhi);
        *(ushort2*)((char*)out + (size_t)n * 128 + (fl << 2)) = o;
    }
}

// ---------------- pool: per-graph sums of bf16 h2 (graph_ids sorted, run-length) ----------------
__global__ void pool_k(const ushort* __restrict__ h, const int* __restrict__ gid,
                       float* __restrict__ gsum, int* __restrict__ gcnt) {
    int lane = threadIdx.x & 63;
    int wpb = blockDim.x >> 6;
    int gw = blockIdx.x * wpb + (threadIdx.x >> 6);
    const int chunk = (N_NODES + NW_POOL - 1) / NW_POOL;
    int n0 = gw * chunk;
    if (n0 >= N_NODES) return;
    int n1 = min(n0 + chunk, N_NODES);
    float acc = 0.f;
    int cur = gid[n0], cnt = 0;
    for (int n = n0; n < n1; n++) {
        int g = gid[n];
        if (g != cur) {
            atomicAdd(&gsum[cur * H + lane], acc);
            if (lane == 0) atomicAdd(&gcnt[cur], cnt);
            cur = g; acc = 0.f; cnt = 0;
        }
        acc += bf2f(h[(size_t)n * H + lane]);
        cnt++;
    }
    atomicAdd(&gsum[cur * H + lane], acc);
    if (lane == 0) atomicAdd(&gcnt[cur], cnt);
}

// ---------------- FC head + sigmoid (weights staged in LDS) ----------------
__global__ void head_k(const float* __restrict__ gsum, const int* __restrict__ gcnt,
                       const float* __restrict__ fc1w, const float* __restrict__ fc1b,
                       const float* __restrict__ fc2w, const float* __restrict__ fc2b,
                       float* __restrict__ out) {
    __shared__ float w1[H * 32];
    __shared__ float w2[32], bb1[32];
    int b = threadIdx.x;
    for (int i = b; i < H * 32; i += 64) w1[i] = fc1w[i];
    if (b < 32) { w2[b] = fc2w[b]; bb1[b] = fc1b[b]; }
    __syncthreads();
    if (b >= N_GRAPHS_C) return;
    float hg[H];
    float inv = 1.0f / fmaxf((float)gcnt[b], 1.0f);
    for (int k = 0; k < H; k++) hg[k] = gsum[b * H + k] * inv;
    float z = fc2b[0];
    for (int j = 0; j < 32; j++) {
        float t = bb1[j];
        for (int k = 0; k < H; k++) t += hg[k] * w1[k * 32 + j];
        z += t * w2[j];
    }
    out[b] = 1.0f / (1.0f + expf(-z));
}

extern "C" void kernel_launch(void* const* d_in, const int* in_sizes, int n_in,
                              void* d_out, int out_size, void* d_ws, size_t ws_size,
                              hipStream_t stream) {
    const float* x        = (const float*)d_in[0];
    const int*   edge_src = (const int*)d_in[1];
    const int*   edge_dst = (const int*)d_in[2];
    const int*   gid      = (const int*)d_in[3];
    const float* bn_gamma = (const float*)d_in[5];
    const float* bn_beta  = (const float*)d_in[6];
    const float* W1       = (const float*)d_in[7];
    const float* b1       = (const float*)d_in[8];
    const float* W2       = (const float*)d_in[9];
    const float* b2       = (const float*)d_in[10];
    const float* fc1w     = (const float*)d_in[11];
    const float* fc1b     = (const float*)d_in[12];
    const float* fc2w     = (const float*)d_in[13];
    const float* fc2b     = (const float*)d_in[14];
    float* out = (float*)d_out;

    // ---- workspace layout ----
    char* ws = (char*)d_ws;
    size_t off = 0;
    auto alloc = [&](size_t bytes) { void* p = ws + off; off += (bytes + 255) & ~(size_t)255; return p; };
    // zero-region: bnsum[86] bnsq[86] bcnt[391] gsum[4096] gcnt[64]  (one memset)
    const size_t ZW = IN_F + IN_F + N_BKT + N_GRAPHS_C * H + N_GRAPHS_C;
    float* zreg  = (float*)alloc(ZW * sizeof(float));
    float* bnsum = zreg;
    float* bnsq  = bnsum + IN_F;
    int*   bcnt  = (int*)(bnsq + IN_F);
    float* gsum  = (float*)(bcnt + N_BKT);
    int*   gcnt  = (int*)(gsum + N_GRAPHS_C * H);
    float* W1p     = (float*)alloc(IN_F * H * sizeof(float));
    float* c1      = (float*)alloc(H * sizeof(float));
    int*   bstart  = (int*)alloc((N_BKT + 1) * sizeof(int));
    int*   gcursor = (int*)alloc(N_BKT * sizeof(int));
    int*   rs      = (int*)alloc(N_NODES * sizeof(int));
    int*   csr     = (int*)alloc((size_t)N_EDGES * sizeof(int));
    ushort* gbuf   = (ushort*)alloc((size_t)N_NODES * H * sizeof(ushort));  // bf16 g1/g2 (12.8 MB)
    ushort* h1     = (ushort*)alloc((size_t)N_NODES * H * sizeof(ushort));  // bf16 h1, then h2 (12.8 MB)
    // ebkt (6.4 MB packed) aliases gbuf: consumed by bucket_fill_k BEFORE gemm writes gbuf.
    unsigned* ebkt = (unsigned*)gbuf;

    hipMemsetAsync(zreg, 0, ZW * sizeof(float), stream);

    // ---- fused BN stats + bucket counts ----
    bn_count_k<<<BC_GRID, 256, 0, stream>>>(x, edge_dst, bnsum, bnsq, bcnt);
    // ---- fused bucket scan + BN fold ----
    scanprep_k<<<1, 512, 0, stream>>>(bcnt, bstart, gcursor, bnsum, bnsq,
                                      bn_gamma, bn_beta, W1, b1, W1p, c1);
    // ---- CSR build ----
    bucket_scatter_k<<<SC_GRID, 256, 0, stream>>>(edge_src, edge_dst, gcursor, ebkt);
    bucket_fill_k<<<N_BKT, 256, 0, stream>>>(ebkt, bstart, rs, csr);

    // ---- layer 1 ----
    gemm_f32_k<<<(N_NODES + 63) / 64, 256, 0, stream>>>(x, W1p, c1, gbuf, N_NODES);
    gather_k<<<(N_NODES + 3) / 4, 256, 0, stream>>>(gbuf, rs, csr, h1);

    // ---- layer 2 ----
    gemm_bf16_k<<<(N_NODES + 63) / 64, 256, 0, stream>>>(h1, W2, b2, gbuf, N_NODES);
    // gather2 writes h2 into the (now dead) h1 buffer
    gather_k<<<(N_NODES + 3) / 4, 256, 0, stream>>>(gbuf, rs, csr, h1);

    // ---- pool + head ----
    pool_k<<<NW_POOL / 4, 256, 0, stream>>>(h1, gid, gsum, gcnt);
    head_k<<<1, 64, 0, stream>>>(gsum, gcnt, fc1w, fc1b, fc2w, fc2b, out);
}

// Round 10
// 398.803 us; speedup vs baseline: 1.1942x; 1.1942x over previous
//
#include <hip/hip_runtime.h>

#define N_NODES 100000
#define N_EDGES 1600000
#define N_GRAPHS_C 64
#define IN_F 86
#define H 64
#define N_BKT 391            // ceil(100000/256), bucket = dst >> 8
#define SC_EPT 8             // edges per thread in bucket passes
#define SC_TILE 2048         // 256 threads * 8
#define SC_GRID 782          // ceil(1.6M / 2048)
#define BC_GRID 1024         // bn+count grid (>= SC_GRID); 4096 waves
#define NW_POOL 2048         // waves in pool_k
typedef unsigned short ushort;

__device__ inline float bf2f(ushort u) { return __uint_as_float(((unsigned)u) << 16); }
__device__ inline ushort f2bf(float f) {
    unsigned x = __float_as_uint(f);
    return (ushort)((x + 0x7fffu + ((x >> 16) & 1u)) >> 16);  // RNE
}

// ---------------- fused: BN stats + per-bucket edge counts ----------------
// Wave-column BN: lane l owns feats {l, 64+l}; contiguous row chunk per wave.
__global__ void bn_count_k(const float* __restrict__ x, const int* __restrict__ dst,
                           float* __restrict__ bnsum, float* __restrict__ bnsq,
                           int* __restrict__ bcnt) {
    __shared__ float s1[IN_F], s2[IN_F];
    __shared__ int hist[N_BKT];
    int tid = threadIdx.x;
    if (tid < IN_F) { s1[tid] = 0.f; s2[tid] = 0.f; }
    for (int i = tid; i < N_BKT; i += 256) hist[i] = 0;
    __syncthreads();
    // edge histogram (blocks < SC_GRID)
    if (blockIdx.x < SC_GRID) {
        int e0 = blockIdx.x * SC_TILE;
#pragma unroll
        for (int i = 0; i < SC_EPT; i++) {
            int e = e0 + i * 256 + tid;
            if (e < N_EDGES) atomicAdd(&hist[dst[e] >> 8], 1);
        }
    }
    // BN partial sums, wave-column
    const int NWAVE = BC_GRID * 4;
    const int RPW = (N_NODES + NWAVE - 1) / NWAVE;   // 25
    int lane = tid & 63;
    int w = blockIdx.x * 4 + (tid >> 6);
    int r0 = w * RPW;
    int r1 = min(r0 + RPW, N_NODES);
    float sum0 = 0.f, sq0 = 0.f, sum1 = 0.f, sq1 = 0.f;
#pragma unroll 4
    for (int r = r0; r < r1; r++) {
        const float* base = x + (size_t)r * IN_F;
        float v0 = base[lane];
        float v1 = (lane < IN_F - 64) ? base[64 + lane] : 0.f;
        sum0 += v0; sq0 += v0 * v0;
        sum1 += v1; sq1 += v1 * v1;
    }
    atomicAdd(&s1[lane], sum0);
    atomicAdd(&s2[lane], sq0);
    if (lane < IN_F - 64) {
        atomicAdd(&s1[64 + lane], sum1);
        atomicAdd(&s2[64 + lane], sq1);
    }
    __syncthreads();
    if (tid < IN_F) {
        atomicAdd(&bnsum[tid], s1[tid]);
        atomicAdd(&bnsq[tid], s2[tid]);
    }
    if (blockIdx.x < SC_GRID)
        for (int i = tid; i < N_BKT; i += 256) atomicAdd(&bcnt[i], hist[i]);
}

// ---------------- fused: bucket scan + BN-fold prep ----------------
__global__ void scanprep_k(const int* __restrict__ bcnt, int* __restrict__ bstart,
                           int* __restrict__ gcursor,
                           const float* __restrict__ bnsum, const float* __restrict__ bnsq,
                           const float* __restrict__ gamma, const float* __restrict__ beta,
                           const float* __restrict__ W1, const float* __restrict__ b1,
                           float* __restrict__ W1p, float* __restrict__ c1) {
    __shared__ int tmp[512];
    __shared__ float scale[IN_F], shift[IN_F];
    int t = threadIdx.x;
    int v = (t < N_BKT) ? bcnt[t] : 0;
    tmp[t] = v;
    __syncthreads();
    for (int off = 1; off < 512; off <<= 1) {
        int a = (t >= off) ? tmp[t - off] : 0;
        __syncthreads();
        tmp[t] += a;
        __syncthreads();
    }
    if (t < N_BKT) { bstart[t] = tmp[t] - v; gcursor[t] = tmp[t] - v; }
    if (t == N_BKT - 1) bstart[N_BKT] = tmp[t];
    if (t < IN_F) {
        float mean = bnsum[t] * (1.0f / N_NODES);
        float var  = bnsq[t] * (1.0f / N_NODES) - mean * mean;
        float sc = gamma[t] * rsqrtf(var + 1e-5f);
        scale[t] = sc;
        shift[t] = beta[t] - mean * sc;
    }
    __syncthreads();
    for (int idx = t; idx < IN_F * H; idx += 512) W1p[idx] = scale[idx / H] * W1[idx];
    if (t < H) {
        float acc = b1[t];
        for (int i = 0; i < IN_F; i++) acc += shift[i] * W1[i * H + t];
        c1[t] = acc;
    }
}

// ---------------- CSR pass 1: partition edges (packed (src<<8)|dstLow) ----------------
__global__ void bucket_scatter_k(const int* __restrict__ src, const int* __restrict__ dst,
                                 int* __restrict__ gcursor, unsigned* __restrict__ ebkt) {
    __shared__ int hist[N_BKT];
    __shared__ int base[N_BKT];
    int tid = threadIdx.x;
    for (int i = tid; i < N_BKT; i += 256) hist[i] = 0;
    __syncthreads();
    int e0 = blockIdx.x * SC_TILE;
    unsigned pk[SC_EPT];
    int bk[SC_EPT], lo[SC_EPT];
#pragma unroll
    for (int i = 0; i < SC_EPT; i++) {
        int e = e0 + i * 256 + tid;
        if (e < N_EDGES) {
            int d = dst[e];
            pk[i] = ((unsigned)src[e] << 8) | (unsigned)(d & 255);
            bk[i] = d >> 8;
            lo[i] = atomicAdd(&hist[bk[i]], 1);
        }
    }
    __syncthreads();
    for (int i = tid; i < N_BKT; i += 256) base[i] = atomicAdd(&gcursor[i], hist[i]);
    __syncthreads();
#pragma unroll
    for (int i = 0; i < SC_EPT; i++) {
        int e = e0 + i * 256 + tid;
        if (e < N_EDGES) ebkt[base[bk[i]] + lo[i]] = pk[i];
    }
}

// ---------------- CSR pass 2: per-bucket degree+scan+fill ----------------
// rs[n] = INCLUSIVE end of node n's csr row. csr entries are BYTE offsets (src*128).
__global__ void bucket_fill_k(const unsigned* __restrict__ ebkt, const int* __restrict__ bstart,
                              int* __restrict__ rs, int* __restrict__ csr) {
    __shared__ int deg[256];
    __shared__ int scn[256];
    __shared__ int cur[256];
    int b = blockIdx.x;
    int tid = threadIdx.x;
    int e0 = bstart[b], e1 = bstart[b + 1];
    deg[tid] = 0;
    __syncthreads();
    for (int e = e0 + tid; e < e1; e += 256) atomicAdd(&deg[ebkt[e] & 255u], 1);
    __syncthreads();
    scn[tid] = deg[tid];
    __syncthreads();
    for (int off = 1; off < 256; off <<= 1) {
        int a = (tid >= off) ? scn[tid - off] : 0;
        __syncthreads();
        scn[tid] += a;
        __syncthreads();
    }
    int node = (b << 8) + tid;
    if (node < N_NODES) rs[node] = e0 + scn[tid];
    cur[tid] = e0 + scn[tid] - deg[tid];
    __syncthreads();
    for (int e = e0 + tid; e < e1; e += 256) {
        unsigned p = ebkt[e];
        int pos = atomicAdd(&cur[p & 255u], 1);
        csr[pos] = (int)((p & ~255u) >> 1);   // src*128 byte offset
    }
}

// ---------------- GEMM (f32 in, K=86): Ybf16 = X @ W + bias ----------------
__global__ __launch_bounds__(256) void gemm_f32_k(const float* __restrict__ X,
                                                  const float* __restrict__ W,
                                                  const float* __restrict__ bias,
                                                  ushort* __restrict__ Y, int N) {
    const int K = IN_F;
    __shared__ __align__(16) float Xl[64][IN_F + 1];
    __shared__ __align__(16) float Wl[IN_F][64];
    int tid = threadIdx.x;
    int row0 = blockIdx.x * 64;
    for (int i = tid; i < K * 64; i += 256) Wl[i / 64][i % 64] = W[i];
    for (int i = tid; i < 64 * K; i += 256) {
        int r = i / K, c = i % K;
        Xl[r][c] = (row0 + r < N) ? X[(size_t)(row0 + r) * K + c] : 0.f;
    }
    __syncthreads();
    int cg = tid & 15, rg = tid >> 4;
    float4 b4 = *(const float4*)&bias[cg * 4];
    float acc[4][4];
    for (int i = 0; i < 4; i++) { acc[i][0] = b4.x; acc[i][1] = b4.y; acc[i][2] = b4.z; acc[i][3] = b4.w; }
    for (int k = 0; k < K; k++) {
        float4 w = *(const float4*)&Wl[k][cg * 4];
        float x0 = Xl[rg * 4 + 0][k];
        float x1 = Xl[rg * 4 + 1][k];
        float x2 = Xl[rg * 4 + 2][k];
        float x3 = Xl[rg * 4 + 3][k];
        acc[0][0] += x0 * w.x; acc[0][1] += x0 * w.y; acc[0][2] += x0 * w.z; acc[0][3] += x0 * w.w;
        acc[1][0] += x1 * w.x; acc[1][1] += x1 * w.y; acc[1][2] += x1 * w.z; acc[1][3] += x1 * w.w;
        acc[2][0] += x2 * w.x; acc[2][1] += x2 * w.y; acc[2][2] += x2 * w.z; acc[2][3] += x2 * w.w;
        acc[3][0] += x3 * w.x; acc[3][1] += x3 * w.y; acc[3][2] += x3 * w.z; acc[3][3] += x3 * w.w;
    }
    for (int i = 0; i < 4; i++) {
        int gr = row0 + rg * 4 + i;
        if (gr < N) {
            ushort4 o;
            o.x = f2bf(acc[i][0]); o.y = f2bf(acc[i][1]);
            o.z = f2bf(acc[i][2]); o.w = f2bf(acc[i][3]);
            *(ushort4*)&Y[(size_t)gr * 64 + cg * 4] = o;
        }
    }
}

// ---------------- GEMM (bf16 in, K=64): Ybf16 = X @ W + bias ----------------
__global__ __launch_bounds__(256) void gemm_bf16_k(const ushort* __restrict__ X,
                                                   const float* __restrict__ W,
                                                   const float* __restrict__ bias,
                                                   ushort* __restrict__ Y, int N) {
    const int K = H;
    __shared__ __align__(16) float Xl[64][H + 1];
    __shared__ __align__(16) float Wl[H][64];
    int tid = threadIdx.x;
    int row0 = blockIdx.x * 64;
    for (int i = tid; i < K * 64; i += 256) Wl[i / 64][i % 64] = W[i];
    for (int i = tid; i < 64 * 16; i += 256) {
        int r = i >> 4, c4 = (i & 15) * 4;
        if (row0 + r < N) {
            ushort4 u = *(const ushort4*)&X[(size_t)(row0 + r) * K + c4];
            Xl[r][c4 + 0] = bf2f(u.x); Xl[r][c4 + 1] = bf2f(u.y);
            Xl[r][c4 + 2] = bf2f(u.z); Xl[r][c4 + 3] = bf2f(u.w);
        } else {
            Xl[r][c4 + 0] = 0.f; Xl[r][c4 + 1] = 0.f;
            Xl[r][c4 + 2] = 0.f; Xl[r][c4 + 3] = 0.f;
        }
    }
    __syncthreads();
    int cg = tid & 15, rg = tid >> 4;
    float4 b4 = *(const float4*)&bias[cg * 4];
    float acc[4][4];
    for (int i = 0; i < 4; i++) { acc[i][0] = b4.x; acc[i][1] = b4.y; acc[i][2] = b4.z; acc[i][3] = b4.w; }
    for (int k = 0; k < K; k++) {
        float4 w = *(const float4*)&Wl[k][cg * 4];
        float x0 = Xl[rg * 4 + 0][k];
        float x1 = Xl[rg * 4 + 1][k];
        float x2 = Xl[rg * 4 + 2][k];
        float x3 = Xl[rg * 4 + 3][k];
        acc[0][0] += x0 * w.x; acc[0][1] += x0 * w.y; acc[0][2] += x0 * w.z; acc[0][3] += x0 * w.w;
        acc[1][0] += x1 * w.x; acc[1][1] += x1 * w.y; acc[1][2] += x1 * w.z; acc[1][3] += x1 * w.w;
        acc[2][0] += x2 * w.x; acc[2][1] += x2 * w.y; acc[2][2] += x2 * w.z; acc[2][3] += x2 * w.w;
        acc[3][0] += x3 * w.x; acc[3][1] += x3 * w.y; acc[3][2] += x3 * w.z; acc[3][3] += x3 * w.w;
    }
    for (int i = 0; i < 4; i++) {
        int gr = row0 + rg * 4 + i;
        if (gr < N) {
            ushort4 o;
            o.x = f2bf(acc[i][0]); o.y = f2bf(acc[i][1]);
            o.z = f2bf(acc[i][2]); o.w = f2bf(acc[i][3]);
            *(ushort4*)&Y[(size_t)gr * 64 + cg * 4] = o;
        }
    }
}

// ---------------- gather core: half-wave paired rows, uint loads ----------------
__device__ inline void gather_row2(const char* __restrict__ gB, const int* __restrict__ csr,
                                   int start, int end, int lane, float& olo, float& ohi) {
    int half = lane >> 5;
    int fl = lane & 31;
    const char* gL = gB + (fl << 2);
    float lo0 = 0.f, lo1 = 0.f, lo2 = 0.f, lo3 = 0.f;
    float lo4 = 0.f, lo5 = 0.f, lo6 = 0.f, lo7 = 0.f;
    float hi0 = 0.f, hi1 = 0.f, hi2 = 0.f, hi3 = 0.f;
    float hi4 = 0.f, hi5 = 0.f, hi6 = 0.f, hi7 = 0.f;
    for (int j0 = start; j0 < end; j0 += 64) {
        int cnt = min(64, end - j0);
        int myoff = (lane < cnt) ? csr[j0 + lane] : 0;
        int j = 0;
        for (; j + 16 <= cnt; j += 16) {
            int s0 = __shfl(myoff, j + 0 + half, 64);
            int s1 = __shfl(myoff, j + 2 + half, 64);
            int s2 = __shfl(myoff, j + 4 + half, 64);
            int s3 = __shfl(myoff, j + 6 + half, 64);
            int s4 = __shfl(myoff, j + 8 + half, 64);
            int s5 = __shfl(myoff, j + 10 + half, 64);
            int s6 = __shfl(myoff, j + 12 + half, 64);
            int s7 = __shfl(myoff, j + 14 + half, 64);
            unsigned u0 = *(const unsigned*)(gL + s0);
            unsigned u1 = *(const unsigned*)(gL + s1);
            unsigned u2 = *(const unsigned*)(gL + s2);
            unsigned u3 = *(const unsigned*)(gL + s3);
            unsigned u4 = *(const unsigned*)(gL + s4);
            unsigned u5 = *(const unsigned*)(gL + s5);
            unsigned u6 = *(const unsigned*)(gL + s6);
            unsigned u7 = *(const unsigned*)(gL + s7);
            lo0 += __uint_as_float(u0 << 16); hi0 += __uint_as_float(u0 & 0xffff0000u);
            lo1 += __uint_as_float(u1 << 16); hi1 += __uint_as_float(u1 & 0xffff0000u);
            lo2 += __uint_as_float(u2 << 16); hi2 += __uint_as_float(u2 & 0xffff0000u);
            lo3 += __uint_as_float(u3 << 16); hi3 += __uint_as_float(u3 & 0xffff0000u);
            lo4 += __uint_as_float(u4 << 16); hi4 += __uint_as_float(u4 & 0xffff0000u);
            lo5 += __uint_as_float(u5 << 16); hi5 += __uint_as_float(u5 & 0xffff0000u);
            lo6 += __uint_as_float(u6 << 16); hi6 += __uint_as_float(u6 & 0xffff0000u);
            lo7 += __uint_as_float(u7 << 16); hi7 += __uint_as_float(u7 & 0xffff0000u);
        }
        for (; j < cnt; j += 2) {
            int idx = j + half;
            int s = __shfl(myoff, (idx < cnt) ? idx : (cnt - 1), 64);
            unsigned u = *(const unsigned*)(gL + s);
            if (idx < cnt) {
                lo0 += __uint_as_float(u << 16);
                hi0 += __uint_as_float(u & 0xffff0000u);
            }
        }
    }
    float lo = ((lo0 + lo1) + (lo2 + lo3)) + ((lo4 + lo5) + (lo6 + lo7));
    float hi = ((hi0 + hi1) + (hi2 + hi3)) + ((hi4 + hi5) + (hi6 + hi7));
    lo += __shfl_xor(lo, 32, 64);
    hi += __shfl_xor(hi, 32, 64);
    olo = lo; ohi = hi;
}

// ---------------- gather: h[n] = relu(mean in-nbr g or g[n]) -> bf16 ----------------
__global__ void gather_k(const ushort* __restrict__ g, const int* __restrict__ rs,
                         const int* __restrict__ csr, ushort* __restrict__ out) {
    int lane = threadIdx.x & 63;
    int n = blockIdx.x * 4 + (threadIdx.x >> 6);
    if (n >= N_NODES) return;
    int start = (n == 0) ? 0 : rs[n - 1];
    int end = rs[n];
    float lo, hi;
    gather_row2((const char*)g, csr, start, end, lane, lo, hi);
    int d = end - start;
    int fl = lane & 31;
    float vlo, vhi;
    if (d > 0) {
        float inv = 1.0f / (float)d;
        vlo = lo * inv; vhi = hi * inv;
    } else {
        unsigned u = *(const unsigned*)((const char*)g + (size_t)n * 128 + (fl << 2));
        vlo = __uint_as_float(u << 16);
        vhi = __uint_as_float(u & 0xffff0000u);
    }
    vlo = fmaxf(vlo, 0.f); vhi = fmaxf(vhi, 0.f);
    if (lane < 32) {
        ushort2 o; o.x = f2bf(vlo); o.y = f2bf(vhi);
        *(ushort2*)((char*)out + (size_t)n * 128 + (fl << 2)) = o;
    }
}

// ---------------- pool: per-graph sums of bf16 h2 (graph_ids sorted, run-length) ----------------
__global__ void pool_k(const ushort* __restrict__ h, const int* __restrict__ gid,
                       float* __restrict__ gsum, int* __restrict__ gcnt) {
    int lane = threadIdx.x & 63;
    int wpb = blockDim.x >> 6;
    int gw = blockIdx.x * wpb + (threadIdx.x >> 6);
    const int chunk = (N_NODES + NW_POOL - 1) / NW_POOL;
    int n0 = gw * chunk;
    if (n0 >= N_NODES) return;
    int n1 = min(n0 + chunk, N_NODES);
    float acc = 0.f;
    int cur = gid[n0], cnt = 0;
    for (int n = n0; n < n1; n++) {
        int g = gid[n];
        if (g != cur) {
            atomicAdd(&gsum[cur * H + lane], acc);
            if (lane == 0) atomicAdd(&gcnt[cur], cnt);
            cur = g; acc = 0.f; cnt = 0;
        }
        acc += bf2f(h[(size_t)n * H + lane]);
        cnt++;
    }
    atomicAdd(&gsum[cur * H + lane], acc);
    if (lane == 0) atomicAdd(&gcnt[cur], cnt);
}

// ---------------- FC head + sigmoid (weights staged in LDS) ----------------
__global__ void head_k(const float* __restrict__ gsum, const int* __restrict__ gcnt,
                       const float* __restrict__ fc1w, const float* __restrict__ fc1b,
                       const float* __restrict__ fc2w, const float* __restrict__ fc2b,
                       float* __restrict__ out) {
    __shared__ float w1[H * 32];
    __shared__ float w2[32], bb1[32];
    int b = threadIdx.x;
    for (int i = b; i < H * 32; i += 64) w1[i] = fc1w[i];
    if (b < 32) { w2[b] = fc2w[b]; bb1[b] = fc1b[b]; }
    __syncthreads();
    if (b >= N_GRAPHS_C) return;
    float hg[H];
    float inv = 1.0f / fmaxf((float)gcnt[b], 1.0f);
    for (int k = 0; k < H; k++) hg[k] = gsum[b * H + k] * inv;
    float z = fc2b[0];
    for (int j = 0; j < 32; j++) {
        float t = bb1[j];
        for (int k = 0; k < H; k++) t += hg[k] * w1[k * 32 + j];
        z += t * w2[j];
    }
    out[b] = 1.0f / (1.0f + expf(-z));
}

extern "C" void kernel_launch(void* const* d_in, const int* in_sizes, int n_in,
                              void* d_out, int out_size, void* d_ws, size_t ws_size,
                              hipStream_t stream) {
    const float* x        = (const float*)d_in[0];
    const int*   edge_src = (const int*)d_in[1];
    const int*   edge_dst = (const int*)d_in[2];
    const int*   gid      = (const int*)d_in[3];
    const float* bn_gamma = (const float*)d_in[5];
    const float* bn_beta  = (const float*)d_in[6];
    const float* W1       = (const float*)d_in[7];
    const float* b1       = (const float*)d_in[8];
    const float* W2       = (const float*)d_in[9];
    const float* b2       = (const float*)d_in[10];
    const float* fc1w     = (const float*)d_in[11];
    const float* fc1b     = (const float*)d_in[12];
    const float* fc2w     = (const float*)d_in[13];
    const float* fc2b     = (const float*)d_in[14];
    float* out = (float*)d_out;

    // ---- workspace layout ----
    char* ws = (char*)d_ws;
    size_t off = 0;
    auto alloc = [&](size_t bytes) { void* p = ws + off; off += (bytes + 255) & ~(size_t)255; return p; };
    // zero-region: bnsum[86] bnsq[86] bcnt[391] gsum[4096] gcnt[64]  (one memset)
    const size_t ZW = IN_F + IN_F + N_BKT + N_GRAPHS_C * H + N_GRAPHS_C;
    float* zreg  = (float*)alloc(ZW * sizeof(float));
    float* bnsum = zreg;
    float* bnsq  = bnsum + IN_F;
    int*   bcnt  = (int*)(bnsq + IN_F);
    float* gsum  = (float*)(bcnt + N_BKT);
    int*   gcnt  = (int*)(gsum + N_GRAPHS_C * H);
    float* W1p     = (float*)alloc(IN_F * H * sizeof(float));
    float* c1      = (float*)alloc(H * sizeof(float));
    int*   bstart  = (int*)alloc((N_BKT + 1) * sizeof(int));
    int*   gcursor = (int*)alloc(N_BKT * sizeof(int));
    int*   rs      = (int*)alloc(N_NODES * sizeof(int));
    int*   csr     = (int*)alloc((size_t)N_EDGES * sizeof(int));
    ushort* gbuf   = (ushort*)alloc((size_t)N_NODES * H * sizeof(ushort));  // bf16 g1/g2 (12.8 MB)
    ushort* h1     = (ushort*)alloc((size_t)N_NODES * H * sizeof(ushort));  // bf16 h1, then h2 (12.8 MB)
    // ebkt (6.4 MB packed) aliases gbuf: consumed by bucket_fill_k BEFORE gemm writes gbuf.
    unsigned* ebkt = (unsigned*)gbuf;

    hipMemsetAsync(zreg, 0, ZW * sizeof(float), stream);

    // ---- fused BN stats + bucket counts ----
    bn_count_k<<<BC_GRID, 256, 0, stream>>>(x, edge_dst, bnsum, bnsq, bcnt);
    // ---- fused bucket scan + BN fold ----
    scanprep_k<<<1, 512, 0, stream>>>(bcnt, bstart, gcursor, bnsum, bnsq,
                                      bn_gamma, bn_beta, W1, b1, W1p, c1);
    // ---- CSR build ----
    bucket_scatter_k<<<SC_GRID, 256, 0, stream>>>(edge_src, edge_dst, gcursor, ebkt);
    bucket_fill_k<<<N_BKT, 256, 0, stream>>>(ebkt, bstart, rs, csr);

    // ---- layer 1 ----
    gemm_f32_k<<<(N_NODES + 63) / 64, 256, 0, stream>>>(x, W1p, c1, gbuf, N_NODES);
    gather_k<<<(N_NODES + 3) / 4, 256, 0, stream>>>(gbuf, rs, csr, h1);

    // ---- layer 2 ----
    gemm_bf16_k<<<(N_NODES + 63) / 64, 256, 0, stream>>>(h1, W2, b2, gbuf, N_NODES);
    // gather2 writes h2 into the (now dead) h1 buffer
    gather_k<<<(N_NODES + 3) / 4, 256, 0, stream>>>(gbuf, rs, csr, h1);

    // ---- pool + head ----
    pool_k<<<NW_POOL / 4, 256, 0, stream>>>(h1, gid, gsum, gcnt);
    head_k<<<1, 64, 0, stream>>>(gsum, gcnt, fc1w, fc1b, fc2w, fc2b, out);
}

// Round 11
// 384.365 us; speedup vs baseline: 1.2391x; 1.0376x over previous
//
#include <hip/hip_runtime.h>

#define N_NODES 100000
#define N_EDGES 1600000
#define N_GRAPHS_C 64
#define IN_F 86
#define H 64
#define N_BKT 391            // ceil(100000/256), bucket = dst >> 8
#define SC_EPT 8             // edges per thread in bucket passes
#define SC_TILE 2048         // 256 threads * 8
#define SC_GRID 782          // ceil(1.6M / 2048)
#define BC_GRID 1024         // bn+count grid (>= SC_GRID); 4096 waves
#define NW_POOL 2048         // waves in pool_k
typedef unsigned short ushort;

__device__ inline float bf2f(ushort u) { return __uint_as_float(((unsigned)u) << 16); }
__device__ inline ushort f2bf(float f) {
    unsigned x = __float_as_uint(f);
    return (ushort)((x + 0x7fffu + ((x >> 16) & 1u)) >> 16);  // RNE
}

// ---------------- fused: BN stats + per-bucket edge counts ----------------
// Wave-column BN: lane l owns feats {l, 64+l}; contiguous row chunk per wave.
__global__ void bn_count_k(const float* __restrict__ x, const int* __restrict__ dst,
                           float* __restrict__ bnsum, float* __restrict__ bnsq,
                           int* __restrict__ bcnt) {
    __shared__ float s1[IN_F], s2[IN_F];
    __shared__ int hist[N_BKT];
    int tid = threadIdx.x;
    if (tid < IN_F) { s1[tid] = 0.f; s2[tid] = 0.f; }
    for (int i = tid; i < N_BKT; i += 256) hist[i] = 0;
    __syncthreads();
    if (blockIdx.x < SC_GRID) {
        int e0 = blockIdx.x * SC_TILE;
#pragma unroll
        for (int i = 0; i < SC_EPT; i++) {
            int e = e0 + i * 256 + tid;
            if (e < N_EDGES) atomicAdd(&hist[dst[e] >> 8], 1);
        }
    }
    const int NWAVE = BC_GRID * 4;
    const int RPW = (N_NODES + NWAVE - 1) / NWAVE;   // 25
    int lane = tid & 63;
    int w = blockIdx.x * 4 + (tid >> 6);
    int r0 = w * RPW;
    int r1 = min(r0 + RPW, N_NODES);
    float sum0 = 0.f, sq0 = 0.f, sum1 = 0.f, sq1 = 0.f;
#pragma unroll 4
    for (int r = r0; r < r1; r++) {
        const float* base = x + (size_t)r * IN_F;
        float v0 = base[lane];
        float v1 = (lane < IN_F - 64) ? base[64 + lane] : 0.f;
        sum0 += v0; sq0 += v0 * v0;
        sum1 += v1; sq1 += v1 * v1;
    }
    atomicAdd(&s1[lane], sum0);
    atomicAdd(&s2[lane], sq0);
    if (lane < IN_F - 64) {
        atomicAdd(&s1[64 + lane], sum1);
        atomicAdd(&s2[64 + lane], sq1);
    }
    __syncthreads();
    if (tid < IN_F) {
        atomicAdd(&bnsum[tid], s1[tid]);
        atomicAdd(&bnsq[tid], s2[tid]);
    }
    if (blockIdx.x < SC_GRID)
        for (int i = tid; i < N_BKT; i += 256) atomicAdd(&bcnt[i], hist[i]);
}

// ---------------- fused: bucket scan + BN-fold prep ----------------
__global__ void scanprep_k(const int* __restrict__ bcnt, int* __restrict__ bstart,
                           int* __restrict__ gcursor,
                           const float* __restrict__ bnsum, const float* __restrict__ bnsq,
                           const float* __restrict__ gamma, const float* __restrict__ beta,
                           const float* __restrict__ W1, const float* __restrict__ b1,
                           float* __restrict__ W1p, float* __restrict__ c1) {
    __shared__ int tmp[512];
    __shared__ float scale[IN_F], shift[IN_F];
    int t = threadIdx.x;
    int v = (t < N_BKT) ? bcnt[t] : 0;
    tmp[t] = v;
    __syncthreads();
    for (int off = 1; off < 512; off <<= 1) {
        int a = (t >= off) ? tmp[t - off] : 0;
        __syncthreads();
        tmp[t] += a;
        __syncthreads();
    }
    if (t < N_BKT) { bstart[t] = tmp[t] - v; gcursor[t] = tmp[t] - v; }
    if (t == N_BKT - 1) bstart[N_BKT] = tmp[t];
    if (t < IN_F) {
        float mean = bnsum[t] * (1.0f / N_NODES);
        float var  = bnsq[t] * (1.0f / N_NODES) - mean * mean;
        float sc = gamma[t] * rsqrtf(var + 1e-5f);
        scale[t] = sc;
        shift[t] = beta[t] - mean * sc;
    }
    __syncthreads();
    for (int idx = t; idx < IN_F * H; idx += 512) W1p[idx] = scale[idx / H] * W1[idx];
    if (t < H) {
        float acc = b1[t];
        for (int i = 0; i < IN_F; i++) acc += shift[i] * W1[i * H + t];
        c1[t] = acc;
    }
}

// ---------------- CSR pass 1: partition edges (packed (src<<8)|dstLow) ----------------
__global__ void bucket_scatter_k(const int* __restrict__ src, const int* __restrict__ dst,
                                 int* __restrict__ gcursor, unsigned* __restrict__ ebkt) {
    __shared__ int hist[N_BKT];
    __shared__ int base[N_BKT];
    int tid = threadIdx.x;
    for (int i = tid; i < N_BKT; i += 256) hist[i] = 0;
    __syncthreads();
    int e0 = blockIdx.x * SC_TILE;
    unsigned pk[SC_EPT];
    int bk[SC_EPT], lo[SC_EPT];
#pragma unroll
    for (int i = 0; i < SC_EPT; i++) {
        int e = e0 + i * 256 + tid;
        if (e < N_EDGES) {
            int d = dst[e];
            pk[i] = ((unsigned)src[e] << 8) | (unsigned)(d & 255);
            bk[i] = d >> 8;
            lo[i] = atomicAdd(&hist[bk[i]], 1);
        }
    }
    __syncthreads();
    for (int i = tid; i < N_BKT; i += 256) base[i] = atomicAdd(&gcursor[i], hist[i]);
    __syncthreads();
#pragma unroll
    for (int i = 0; i < SC_EPT; i++) {
        int e = e0 + i * 256 + tid;
        if (e < N_EDGES) ebkt[base[bk[i]] + lo[i]] = pk[i];
    }
}

// ---------------- CSR pass 2: per-bucket degree+scan+fill ----------------
// rs[n] = INCLUSIVE end of node n's csr row. csr entries are BYTE offsets (src*128).
__global__ void bucket_fill_k(const unsigned* __restrict__ ebkt, const int* __restrict__ bstart,
                              int* __restrict__ rs, int* __restrict__ csr) {
    __shared__ int deg[256];
    __shared__ int scn[256];
    __shared__ int cur[256];
    int b = blockIdx.x;
    int tid = threadIdx.x;
    int e0 = bstart[b], e1 = bstart[b + 1];
    deg[tid] = 0;
    __syncthreads();
    for (int e = e0 + tid; e < e1; e += 256) atomicAdd(&deg[ebkt[e] & 255u], 1);
    __syncthreads();
    scn[tid] = deg[tid];
    __syncthreads();
    for (int off = 1; off < 256; off <<= 1) {
        int a = (tid >= off) ? scn[tid - off] : 0;
        __syncthreads();
        scn[tid] += a;
        __syncthreads();
    }
    int node = (b << 8) + tid;
    if (node < N_NODES) rs[node] = e0 + scn[tid];
    cur[tid] = e0 + scn[tid] - deg[tid];
    __syncthreads();
    for (int e = e0 + tid; e < e1; e += 256) {
        unsigned p = ebkt[e];
        int pos = atomicAdd(&cur[p & 255u], 1);
        csr[pos] = (int)((p & ~255u) >> 1);   // src*128 byte offset
    }
}

// ---------------- GEMM (f32 in, K=86): Ybf16 = X @ W + bias ----------------
// X staged TRANSPOSED in LDS (Xt[k][r], stride 68 floats = 16B-aligned) so the
// k-loop reads the 4-row X fragment as one ds_read_b128.
__global__ __launch_bounds__(256) void gemm_f32_k(const float* __restrict__ X,
                                                  const float* __restrict__ W,
                                                  const float* __restrict__ bias,
                                                  ushort* __restrict__ Y, int N) {
    const int K = IN_F;
    __shared__ __align__(16) float Xt[IN_F][68];
    __shared__ __align__(16) float Wl[IN_F][64];
    int tid = threadIdx.x;
    int row0 = blockIdx.x * 64;
    for (int i = tid; i < K * 64; i += 256) Wl[i / 64][i % 64] = W[i];
    for (int i = tid; i < 64 * K; i += 256) {
        int r = i / K, c = i % K;
        Xt[c][r] = (row0 + r < N) ? X[(size_t)(row0 + r) * K + c] : 0.f;
    }
    __syncthreads();
    int cg = tid & 15, rg = tid >> 4;
    float4 b4 = *(const float4*)&bias[cg * 4];
    float acc[4][4];
    for (int i = 0; i < 4; i++) { acc[i][0] = b4.x; acc[i][1] = b4.y; acc[i][2] = b4.z; acc[i][3] = b4.w; }
    for (int k = 0; k < K; k++) {
        float4 w = *(const float4*)&Wl[k][cg * 4];
        float4 xv = *(const float4*)&Xt[k][rg * 4];
        acc[0][0] += xv.x * w.x; acc[0][1] += xv.x * w.y; acc[0][2] += xv.x * w.z; acc[0][3] += xv.x * w.w;
        acc[1][0] += xv.y * w.x; acc[1][1] += xv.y * w.y; acc[1][2] += xv.y * w.z; acc[1][3] += xv.y * w.w;
        acc[2][0] += xv.z * w.x; acc[2][1] += xv.z * w.y; acc[2][2] += xv.z * w.z; acc[2][3] += xv.z * w.w;
        acc[3][0] += xv.w * w.x; acc[3][1] += xv.w * w.y; acc[3][2] += xv.w * w.z; acc[3][3] += xv.w * w.w;
    }
    for (int i = 0; i < 4; i++) {
        int gr = row0 + rg * 4 + i;
        if (gr < N) {
            ushort4 o;
            o.x = f2bf(acc[i][0]); o.y = f2bf(acc[i][1]);
            o.z = f2bf(acc[i][2]); o.w = f2bf(acc[i][3]);
            *(ushort4*)&Y[(size_t)gr * 64 + cg * 4] = o;
        }
    }
}

// ---------------- GEMM (bf16 in, K=64): Ybf16 = X @ W + bias ----------------
__global__ __launch_bounds__(256) void gemm_bf16_k(const ushort* __restrict__ X,
                                                   const float* __restrict__ W,
                                                   const float* __restrict__ bias,
                                                   ushort* __restrict__ Y, int N) {
    const int K = H;
    __shared__ __align__(16) float Xt[H][68];
    __shared__ __align__(16) float Wl[H][64];
    int tid = threadIdx.x;
    int row0 = blockIdx.x * 64;
    for (int i = tid; i < K * 64; i += 256) Wl[i / 64][i % 64] = W[i];
    for (int i = tid; i < 64 * 16; i += 256) {
        int r = i >> 4, c4 = (i & 15) * 4;
        if (row0 + r < N) {
            ushort4 u = *(const ushort4*)&X[(size_t)(row0 + r) * K + c4];
            Xt[c4 + 0][r] = bf2f(u.x); Xt[c4 + 1][r] = bf2f(u.y);
            Xt[c4 + 2][r] = bf2f(u.z); Xt[c4 + 3][r] = bf2f(u.w);
        } else {
            Xt[c4 + 0][r] = 0.f; Xt[c4 + 1][r] = 0.f;
            Xt[c4 + 2][r] = 0.f; Xt[c4 + 3][r] = 0.f;
        }
    }
    __syncthreads();
    int cg = tid & 15, rg = tid >> 4;
    float4 b4 = *(const float4*)&bias[cg * 4];
    float acc[4][4];
    for (int i = 0; i < 4; i++) { acc[i][0] = b4.x; acc[i][1] = b4.y; acc[i][2] = b4.z; acc[i][3] = b4.w; }
    for (int k = 0; k < K; k++) {
        float4 w = *(const float4*)&Wl[k][cg * 4];
        float4 xv = *(const float4*)&Xt[k][rg * 4];
        acc[0][0] += xv.x * w.x; acc[0][1] += xv.x * w.y; acc[0][2] += xv.x * w.z; acc[0][3] += xv.x * w.w;
        acc[1][0] += xv.y * w.x; acc[1][1] += xv.y * w.y; acc[1][2] += xv.y * w.z; acc[1][3] += xv.y * w.w;
        acc[2][0] += xv.z * w.x; acc[2][1] += xv.z * w.y; acc[2][2] += xv.z * w.z; acc[2][3] += xv.z * w.w;
        acc[3][0] += xv.w * w.x; acc[3][1] += xv.w * w.y; acc[3][2] += xv.w * w.z; acc[3][3] += xv.w * w.w;
    }
    for (int i = 0; i < 4; i++) {
        int gr = row0 + rg * 4 + i;
        if (gr < N) {
            ushort4 o;
            o.x = f2bf(acc[i][0]); o.y = f2bf(acc[i][1]);
            o.z = f2bf(acc[i][2]); o.w = f2bf(acc[i][3]);
            *(ushort4*)&Y[(size_t)gr * 64 + cg * 4] = o;
        }
    }
}

// ---------------- gather: quad-group (grp=lane>>4, fl=lane&15) ----------------
// One wave load instruction = 4 edges x 128 B = 512 B. One __shfl(myoff, j+grp)
// distributes 4 edge offsets. Cross-group combine: shfl_xor 16/32.
__global__ void gather_k(const ushort* __restrict__ g, const int* __restrict__ rs,
                         const int* __restrict__ csr, ushort* __restrict__ out) {
    int lane = threadIdx.x & 63;
    int n = blockIdx.x * 4 + (threadIdx.x >> 6);
    if (n >= N_NODES) return;
    int start = (n == 0) ? 0 : rs[n - 1];
    int end = rs[n];
    int fl = lane & 15;
    int grp = lane >> 4;
    const char* gL = (const char*)g + (fl << 3);
    float a0 = 0.f, a1 = 0.f, a2 = 0.f, a3 = 0.f;
    float b0 = 0.f, b1 = 0.f, b2 = 0.f, b3 = 0.f;
    for (int j0 = start; j0 < end; j0 += 64) {
        int cnt = min(64, end - j0);
        int myoff = (lane < cnt) ? csr[j0 + lane] : 0;
        int j = 0;
        for (; j + 8 <= cnt; j += 8) {
            int s0 = __shfl(myoff, j + grp, 64);
            int s1 = __shfl(myoff, j + 4 + grp, 64);
            uint2 u0 = *(const uint2*)(gL + s0);
            uint2 u1 = *(const uint2*)(gL + s1);
            a0 += __uint_as_float(u0.x << 16);
            a1 += __uint_as_float(u0.x & 0xffff0000u);
            a2 += __uint_as_float(u0.y << 16);
            a3 += __uint_as_float(u0.y & 0xffff0000u);
            b0 += __uint_as_float(u1.x << 16);
            b1 += __uint_as_float(u1.x & 0xffff0000u);
            b2 += __uint_as_float(u1.y << 16);
            b3 += __uint_as_float(u1.y & 0xffff0000u);
        }
        for (; j < cnt; j += 4) {
            int idx = j + grp;
            int s = __shfl(myoff, (idx < cnt) ? idx : (cnt - 1), 64);
            uint2 u = *(const uint2*)(gL + s);
            if (idx < cnt) {
                a0 += __uint_as_float(u.x << 16);
                a1 += __uint_as_float(u.x & 0xffff0000u);
                a2 += __uint_as_float(u.y << 16);
                a3 += __uint_as_float(u.y & 0xffff0000u);
            }
        }
    }
    float v0 = a0 + b0, v1 = a1 + b1, v2 = a2 + b2, v3 = a3 + b3;
    v0 += __shfl_xor(v0, 16, 64); v0 += __shfl_xor(v0, 32, 64);
    v1 += __shfl_xor(v1, 16, 64); v1 += __shfl_xor(v1, 32, 64);
    v2 += __shfl_xor(v2, 16, 64); v2 += __shfl_xor(v2, 32, 64);
    v3 += __shfl_xor(v3, 16, 64); v3 += __shfl_xor(v3, 32, 64);
    if (grp == 0) {
        int d = end - start;
        float r0, r1, r2, r3;
        if (d > 0) {
            float inv = 1.0f / (float)d;
            r0 = v0 * inv; r1 = v1 * inv; r2 = v2 * inv; r3 = v3 * inv;
        } else {
            uint2 u = *(const uint2*)((const char*)g + (size_t)n * 128 + (fl << 3));
            r0 = __uint_as_float(u.x << 16);
            r1 = __uint_as_float(u.x & 0xffff0000u);
            r2 = __uint_as_float(u.y << 16);
            r3 = __uint_as_float(u.y & 0xffff0000u);
        }
        ushort4 o;
        o.x = f2bf(fmaxf(r0, 0.f)); o.y = f2bf(fmaxf(r1, 0.f));
        o.z = f2bf(fmaxf(r2, 0.f)); o.w = f2bf(fmaxf(r3, 0.f));
        *(ushort4*)((char*)out + (size_t)n * 128 + (fl << 3)) = o;
    }
}

// ---------------- pool: per-graph sums of bf16 h2 (graph_ids sorted, run-length) ----------------
__global__ void pool_k(const ushort* __restrict__ h, const int* __restrict__ gid,
                       float* __restrict__ gsum, int* __restrict__ gcnt) {
    int lane = threadIdx.x & 63;
    int wpb = blockDim.x >> 6;
    int gw = blockIdx.x * wpb + (threadIdx.x >> 6);
    const int chunk = (N_NODES + NW_POOL - 1) / NW_POOL;
    int n0 = gw * chunk;
    if (n0 >= N_NODES) return;
    int n1 = min(n0 + chunk, N_NODES);
    float acc = 0.f;
    int cur = gid[n0], cnt = 0;
    for (int n = n0; n < n1; n++) {
        int g = gid[n];
        if (g != cur) {
            atomicAdd(&gsum[cur * H + lane], acc);
            if (lane == 0) atomicAdd(&gcnt[cur], cnt);
            cur = g; acc = 0.f; cnt = 0;
        }
        acc += bf2f(h[(size_t)n * H + lane]);
        cnt++;
    }
    atomicAdd(&gsum[cur * H + lane], acc);
    if (lane == 0) atomicAdd(&gcnt[cur], cnt);
}

// ---------------- FC head + sigmoid (weights staged in LDS) ----------------
__global__ void head_k(const float* __restrict__ gsum, const int* __restrict__ gcnt,
                       const float* __restrict__ fc1w, const float* __restrict__ fc1b,
                       const float* __restrict__ fc2w, const float* __restrict__ fc2b,
                       float* __restrict__ out) {
    __shared__ float w1[H * 32];
    __shared__ float w2[32], bb1[32];
    int b = threadIdx.x;
    for (int i = b; i < H * 32; i += 64) w1[i] = fc1w[i];
    if (b < 32) { w2[b] = fc2w[b]; bb1[b] = fc1b[b]; }
    __syncthreads();
    if (b >= N_GRAPHS_C) return;
    float hg[H];
    float inv = 1.0f / fmaxf((float)gcnt[b], 1.0f);
    for (int k = 0; k < H; k++) hg[k] = gsum[b * H + k] * inv;
    float z = fc2b[0];
    for (int j = 0; j < 32; j++) {
        float t = bb1[j];
        for (int k = 0; k < H; k++) t += hg[k] * w1[k * 32 + j];
        z += t * w2[j];
    }
    out[b] = 1.0f / (1.0f + expf(-z));
}

extern "C" void kernel_launch(void* const* d_in, const int* in_sizes, int n_in,
                              void* d_out, int out_size, void* d_ws, size_t ws_size,
                              hipStream_t stream) {
    const float* x        = (const float*)d_in[0];
    const int*   edge_src = (const int*)d_in[1];
    const int*   edge_dst = (const int*)d_in[2];
    const int*   gid      = (const int*)d_in[3];
    const float* bn_gamma = (const float*)d_in[5];
    const float* bn_beta  = (const float*)d_in[6];
    const float* W1       = (const float*)d_in[7];
    const float* b1       = (const float*)d_in[8];
    const float* W2       = (const float*)d_in[9];
    const float* b2       = (const float*)d_in[10];
    const float* fc1w     = (const float*)d_in[11];
    const float* fc1b     = (const float*)d_in[12];
    const float* fc2w     = (const float*)d_in[13];
    const float* fc2b     = (const float*)d_in[14];
    float* out = (float*)d_out;

    // ---- workspace layout ----
    char* ws = (char*)d_ws;
    size_t off = 0;
    auto alloc = [&](size_t bytes) { void* p = ws + off; off += (bytes + 255) & ~(size_t)255; return p; };
    // zero-region: bnsum[86] bnsq[86] bcnt[391] gsum[4096] gcnt[64]  (one memset)
    const size_t ZW = IN_F + IN_F + N_BKT + N_GRAPHS_C * H + N_GRAPHS_C;
    float* zreg  = (float*)alloc(ZW * sizeof(float));
    float* bnsum = zreg;
    float* bnsq  = bnsum + IN_F;
    int*   bcnt  = (int*)(bnsq + IN_F);
    float* gsum  = (float*)(bcnt + N_BKT);
    int*   gcnt  = (int*)(gsum + N_GRAPHS_C * H);
    float* W1p     = (float*)alloc(IN_F * H * sizeof(float));
    float* c1      = (float*)alloc(H * sizeof(float));
    int*   bstart  = (int*)alloc((N_BKT + 1) * sizeof(int));
    int*   gcursor = (int*)alloc(N_BKT * sizeof(int));
    int*   rs      = (int*)alloc(N_NODES * sizeof(int));
    int*   csr     = (int*)alloc((size_t)N_EDGES * sizeof(int));
    ushort* gbuf   = (ushort*)alloc((size_t)N_NODES * H * sizeof(ushort));  // bf16 g1/g2 (12.8 MB)
    ushort* h1     = (ushort*)alloc((size_t)N_NODES * H * sizeof(ushort));  // bf16 h1, then h2 (12.8 MB)
    // ebkt (6.4 MB packed) aliases gbuf: consumed by bucket_fill_k BEFORE gemm writes gbuf.
    unsigned* ebkt = (unsigned*)gbuf;

    hipMemsetAsync(zreg, 0, ZW * sizeof(float), stream);

    // ---- fused BN stats + bucket counts ----
    bn_count_k<<<BC_GRID, 256, 0, stream>>>(x, edge_dst, bnsum, bnsq, bcnt);
    // ---- fused bucket scan + BN fold ----
    scanprep_k<<<1, 512, 0, stream>>>(bcnt, bstart, gcursor, bnsum, bnsq,
                                      bn_gamma, bn_beta, W1, b1, W1p, c1);
    // ---- CSR build ----
    bucket_scatter_k<<<SC_GRID, 256, 0, stream>>>(edge_src, edge_dst, gcursor, ebkt);
    bucket_fill_k<<<N_BKT, 256, 0, stream>>>(ebkt, bstart, rs, csr);

    // ---- layer 1 ----
    gemm_f32_k<<<(N_NODES + 63) / 64, 256, 0, stream>>>(x, W1p, c1, gbuf, N_NODES);
    gather_k<<<(N_NODES + 3) / 4, 256, 0, stream>>>(gbuf, rs, csr, h1);

    // ---- layer 2 ----
    gemm_bf16_k<<<(N_NODES + 63) / 64, 256, 0, stream>>>(h1, W2, b2, gbuf, N_NODES);
    // gather2 writes h2 into the (now dead) h1 buffer
    gather_k<<<(N_NODES + 3) / 4, 256, 0, stream>>>(gbuf, rs, csr, h1);

    // ---- pool + head ----
    pool_k<<<NW_POOL / 4, 256, 0, stream>>>(h1, gid, gsum, gcnt);
    head_k<<<1, 64, 0, stream>>>(gsum, gcnt, fc1w, fc1b, fc2w, fc2b, out);
}

// Round 12
// 360.243 us; speedup vs baseline: 1.3221x; 1.0670x over previous
//
#include <hip/hip_runtime.h>

#define N_NODES 100000
#define N_EDGES 1600000
#define N_GRAPHS_C 64
#define IN_F 86
#define H 64
#define N_BKT 391            // ceil(100000/256), bucket = dst >> 8
#define SC_EPT 8             // edges per thread in bucket passes
#define SC_TILE 2048         // 256 threads * 8
#define SC_GRID 782          // ceil(1.6M / 2048)
#define BC_GRID 1024         // bn+count grid (>= SC_GRID); 4096 waves
typedef unsigned short ushort;

__device__ inline float bf2f(ushort u) { return __uint_as_float(((unsigned)u) << 16); }
__device__ inline ushort f2bf(float f) {
    unsigned x = __float_as_uint(f);
    return (ushort)((x + 0x7fffu + ((x >> 16) & 1u)) >> 16);  // RNE
}

// ---------------- fused: BN stats + per-bucket edge counts ----------------
__global__ void bn_count_k(const float* __restrict__ x, const int* __restrict__ dst,
                           float* __restrict__ bnsum, float* __restrict__ bnsq,
                           int* __restrict__ bcnt) {
    __shared__ float s1[IN_F], s2[IN_F];
    __shared__ int hist[N_BKT];
    int tid = threadIdx.x;
    if (tid < IN_F) { s1[tid] = 0.f; s2[tid] = 0.f; }
    for (int i = tid; i < N_BKT; i += 256) hist[i] = 0;
    __syncthreads();
    if (blockIdx.x < SC_GRID) {
        int e0 = blockIdx.x * SC_TILE;
#pragma unroll
        for (int i = 0; i < SC_EPT; i++) {
            int e = e0 + i * 256 + tid;
            if (e < N_EDGES) atomicAdd(&hist[dst[e] >> 8], 1);
        }
    }
    const int NWAVE = BC_GRID * 4;
    const int RPW = (N_NODES + NWAVE - 1) / NWAVE;   // 25
    int lane = tid & 63;
    int w = blockIdx.x * 4 + (tid >> 6);
    int r0 = w * RPW;
    int r1 = min(r0 + RPW, N_NODES);
    float sum0 = 0.f, sq0 = 0.f, sum1 = 0.f, sq1 = 0.f;
#pragma unroll 4
    for (int r = r0; r < r1; r++) {
        const float* base = x + (size_t)r * IN_F;
        float v0 = base[lane];
        float v1 = (lane < IN_F - 64) ? base[64 + lane] : 0.f;
        sum0 += v0; sq0 += v0 * v0;
        sum1 += v1; sq1 += v1 * v1;
    }
    atomicAdd(&s1[lane], sum0);
    atomicAdd(&s2[lane], sq0);
    if (lane < IN_F - 64) {
        atomicAdd(&s1[64 + lane], sum1);
        atomicAdd(&s2[64 + lane], sq1);
    }
    __syncthreads();
    if (tid < IN_F) {
        atomicAdd(&bnsum[tid], s1[tid]);
        atomicAdd(&bnsq[tid], s2[tid]);
    }
    if (blockIdx.x < SC_GRID)
        for (int i = tid; i < N_BKT; i += 256) atomicAdd(&bcnt[i], hist[i]);
}

// ---------------- fused: bucket scan + BN-fold prep ----------------
__global__ void scanprep_k(const int* __restrict__ bcnt, int* __restrict__ bstart,
                           int* __restrict__ gcursor,
                           const float* __restrict__ bnsum, const float* __restrict__ bnsq,
                           const float* __restrict__ gamma, const float* __restrict__ beta,
                           const float* __restrict__ W1, const float* __restrict__ b1,
                           float* __restrict__ W1p, float* __restrict__ c1) {
    __shared__ int tmp[512];
    __shared__ float scale[IN_F], shift[IN_F];
    int t = threadIdx.x;
    int v = (t < N_BKT) ? bcnt[t] : 0;
    tmp[t] = v;
    __syncthreads();
    for (int off = 1; off < 512; off <<= 1) {
        int a = (t >= off) ? tmp[t - off] : 0;
        __syncthreads();
        tmp[t] += a;
        __syncthreads();
    }
    if (t < N_BKT) { bstart[t] = tmp[t] - v; gcursor[t] = tmp[t] - v; }
    if (t == N_BKT - 1) bstart[N_BKT] = tmp[t];
    if (t < IN_F) {
        float mean = bnsum[t] * (1.0f / N_NODES);
        float var  = bnsq[t] * (1.0f / N_NODES) - mean * mean;
        float sc = gamma[t] * rsqrtf(var + 1e-5f);
        scale[t] = sc;
        shift[t] = beta[t] - mean * sc;
    }
    __syncthreads();
    for (int idx = t; idx < IN_F * H; idx += 512) W1p[idx] = scale[idx / H] * W1[idx];
    if (t < H) {
        float acc = b1[t];
        for (int i = 0; i < IN_F; i++) acc += shift[i] * W1[i * H + t];
        c1[t] = acc;
    }
}

// ---------------- CSR pass 1: partition edges (packed (src<<8)|dstLow) ----------------
__global__ void bucket_scatter_k(const int* __restrict__ src, const int* __restrict__ dst,
                                 int* __restrict__ gcursor, unsigned* __restrict__ ebkt) {
    __shared__ int hist[N_BKT];
    __shared__ int base[N_BKT];
    int tid = threadIdx.x;
    for (int i = tid; i < N_BKT; i += 256) hist[i] = 0;
    __syncthreads();
    int e0 = blockIdx.x * SC_TILE;
    unsigned pk[SC_EPT];
    int bk[SC_EPT], lo[SC_EPT];
#pragma unroll
    for (int i = 0; i < SC_EPT; i++) {
        int e = e0 + i * 256 + tid;
        if (e < N_EDGES) {
            int d = dst[e];
            pk[i] = ((unsigned)src[e] << 8) | (unsigned)(d & 255);
            bk[i] = d >> 8;
            lo[i] = atomicAdd(&hist[bk[i]], 1);
        }
    }
    __syncthreads();
    for (int i = tid; i < N_BKT; i += 256) base[i] = atomicAdd(&gcursor[i], hist[i]);
    __syncthreads();
#pragma unroll
    for (int i = 0; i < SC_EPT; i++) {
        int e = e0 + i * 256 + tid;
        if (e < N_EDGES) ebkt[base[bk[i]] + lo[i]] = pk[i];
    }
}

// ---------------- CSR pass 2: per-bucket degree+scan+fill ----------------
// rs[n] = INCLUSIVE end of node n's csr row. csr entries are BYTE offsets (src*128).
__global__ void bucket_fill_k(const unsigned* __restrict__ ebkt, const int* __restrict__ bstart,
                              int* __restrict__ rs, int* __restrict__ csr) {
    __shared__ int deg[256];
    __shared__ int scn[256];
    __shared__ int cur[256];
    int b = blockIdx.x;
    int tid = threadIdx.x;
    int e0 = bstart[b], e1 = bstart[b + 1];
    deg[tid] = 0;
    __syncthreads();
    for (int e = e0 + tid; e < e1; e += 256) atomicAdd(&deg[ebkt[e] & 255u], 1);
    __syncthreads();
    scn[tid] = deg[tid];
    __syncthreads();
    for (int off = 1; off < 256; off <<= 1) {
        int a = (tid >= off) ? scn[tid - off] : 0;
        __syncthreads();
        scn[tid] += a;
        __syncthreads();
    }
    int node = (b << 8) + tid;
    if (node < N_NODES) rs[node] = e0 + scn[tid];
    cur[tid] = e0 + scn[tid] - deg[tid];
    __syncthreads();
    for (int e = e0 + tid; e < e1; e += 256) {
        unsigned p = ebkt[e];
        int pos = atomicAdd(&cur[p & 255u], 1);
        csr[pos] = (int)((p & ~255u) >> 1);   // src*128 byte offset
    }
}

// ---------------- GEMM (f32 in, K=86): Ybf16 = X @ W + bias ----------------
// X staged TRANSPOSED bf16 in LDS (Xt[k][r], stride 72 ushorts = 8B-aligned rows)
// -> k-loop reads the 4-row fragment as one ds_read_b64; 34.4 KB LDS (4 blk/CU).
__global__ __launch_bounds__(256) void gemm_f32_k(const float* __restrict__ X,
                                                  const float* __restrict__ W,
                                                  const float* __restrict__ bias,
                                                  ushort* __restrict__ Y, int N) {
    const int K = IN_F;
    __shared__ __align__(16) ushort Xt[IN_F][72];
    __shared__ __align__(16) float Wl[IN_F][64];
    int tid = threadIdx.x;
    int row0 = blockIdx.x * 64;
    for (int i = tid; i < K * 64; i += 256) Wl[i / 64][i % 64] = W[i];
    for (int i = tid; i < 64 * K; i += 256) {
        int r = i / K, c = i % K;
        Xt[c][r] = (row0 + r < N) ? f2bf(X[(size_t)(row0 + r) * K + c]) : (ushort)0;
    }
    __syncthreads();
    int cg = tid & 15, rg = tid >> 4;
    float4 b4 = *(const float4*)&bias[cg * 4];
    float acc[4][4];
    for (int i = 0; i < 4; i++) { acc[i][0] = b4.x; acc[i][1] = b4.y; acc[i][2] = b4.z; acc[i][3] = b4.w; }
    for (int k = 0; k < K; k++) {
        float4 w = *(const float4*)&Wl[k][cg * 4];
        ushort4 xu = *(const ushort4*)&Xt[k][rg * 4];
        float x0 = bf2f(xu.x), x1 = bf2f(xu.y), x2 = bf2f(xu.z), x3 = bf2f(xu.w);
        acc[0][0] += x0 * w.x; acc[0][1] += x0 * w.y; acc[0][2] += x0 * w.z; acc[0][3] += x0 * w.w;
        acc[1][0] += x1 * w.x; acc[1][1] += x1 * w.y; acc[1][2] += x1 * w.z; acc[1][3] += x1 * w.w;
        acc[2][0] += x2 * w.x; acc[2][1] += x2 * w.y; acc[2][2] += x2 * w.z; acc[2][3] += x2 * w.w;
        acc[3][0] += x3 * w.x; acc[3][1] += x3 * w.y; acc[3][2] += x3 * w.z; acc[3][3] += x3 * w.w;
    }
    for (int i = 0; i < 4; i++) {
        int gr = row0 + rg * 4 + i;
        if (gr < N) {
            ushort4 o;
            o.x = f2bf(acc[i][0]); o.y = f2bf(acc[i][1]);
            o.z = f2bf(acc[i][2]); o.w = f2bf(acc[i][3]);
            *(ushort4*)&Y[(size_t)gr * 64 + cg * 4] = o;
        }
    }
}

// ---------------- fused GEMM2 + pool: gsum[g] += relu(t @ W2 + b2), gcnt[g] += rows ----------------
// t bf16 [N,64]; per-block run-detection over sorted gids; LDS tree-reduce; ~64 atomics/run.
__global__ __launch_bounds__(256) void gemm2pool_k(const ushort* __restrict__ X,
                                                   const float* __restrict__ W,
                                                   const float* __restrict__ bias,
                                                   const int* __restrict__ gid,
                                                   float* __restrict__ gsum,
                                                   int* __restrict__ gcnt, int N) {
    const int K = H;
    __shared__ __align__(16) ushort Xt[H][72];
    __shared__ __align__(16) float Wl[H][64];
    __shared__ int gl[64];
    __shared__ __align__(16) float red[16][64];
    int tid = threadIdx.x;
    int row0 = blockIdx.x * 64;
    for (int i = tid; i < K * 64; i += 256) Wl[i / 64][i % 64] = W[i];
    for (int i = tid; i < 64 * 16; i += 256) {
        int r = i >> 4, c4 = (i & 15) * 4;
        ushort4 u = (row0 + r < N) ? *(const ushort4*)&X[(size_t)(row0 + r) * K + c4]
                                   : make_ushort4(0, 0, 0, 0);
        Xt[c4 + 0][r] = u.x; Xt[c4 + 1][r] = u.y;
        Xt[c4 + 2][r] = u.z; Xt[c4 + 3][r] = u.w;
    }
    if (tid < 64) gl[tid] = (row0 + tid < N) ? gid[row0 + tid] : -1;
    __syncthreads();
    int cg = tid & 15, rg = tid >> 4;
    float4 b4 = *(const float4*)&bias[cg * 4];
    float acc[4][4];
    for (int i = 0; i < 4; i++) { acc[i][0] = b4.x; acc[i][1] = b4.y; acc[i][2] = b4.z; acc[i][3] = b4.w; }
    for (int k = 0; k < K; k++) {
        float4 w = *(const float4*)&Wl[k][cg * 4];
        ushort4 xu = *(const ushort4*)&Xt[k][rg * 4];
        float x0 = bf2f(xu.x), x1 = bf2f(xu.y), x2 = bf2f(xu.z), x3 = bf2f(xu.w);
        acc[0][0] += x0 * w.x; acc[0][1] += x0 * w.y; acc[0][2] += x0 * w.z; acc[0][3] += x0 * w.w;
        acc[1][0] += x1 * w.x; acc[1][1] += x1 * w.y; acc[1][2] += x1 * w.z; acc[1][3] += x1 * w.w;
        acc[2][0] += x2 * w.x; acc[2][1] += x2 * w.y; acc[2][2] += x2 * w.z; acc[2][3] += x2 * w.w;
        acc[3][0] += x3 * w.x; acc[3][1] += x3 * w.y; acc[3][2] += x3 * w.z; acc[3][3] += x3 * w.w;
    }
    // relu
    for (int i = 0; i < 4; i++)
        for (int j = 0; j < 4; j++) acc[i][j] = fmaxf(acc[i][j], 0.f);
    // pool runs of equal gid (sorted); uniform control flow across block.
    int rstart = 0;
    while (rstart < 64) {
        int g = gl[rstart];
        if (g < 0) break;
        int rend = rstart + 1;
        while (rend < 64 && gl[rend] == g) rend++;
        // per-thread partial over its rows in [rstart, rend)
        float p0 = 0.f, p1 = 0.f, p2 = 0.f, p3 = 0.f;
#pragma unroll
        for (int i = 0; i < 4; i++) {
            int r = rg * 4 + i;
            if (r >= rstart && r < rend) { p0 += acc[i][0]; p1 += acc[i][1]; p2 += acc[i][2]; p3 += acc[i][3]; }
        }
        *(float4*)&red[rg][cg * 4] = make_float4(p0, p1, p2, p3);
        __syncthreads();
        for (int s = 8; s >= 1; s >>= 1) {
            if (rg < s) {
                float4 a = *(float4*)&red[rg][cg * 4];
                float4 b = *(float4*)&red[rg + s][cg * 4];
                *(float4*)&red[rg][cg * 4] = make_float4(a.x + b.x, a.y + b.y, a.z + b.z, a.w + b.w);
            }
            __syncthreads();
        }
        if (rg == 0) {
            atomicAdd(&gsum[g * 64 + cg * 4 + 0], red[0][cg * 4 + 0]);
            atomicAdd(&gsum[g * 64 + cg * 4 + 1], red[0][cg * 4 + 1]);
            atomicAdd(&gsum[g * 64 + cg * 4 + 2], red[0][cg * 4 + 2]);
            atomicAdd(&gsum[g * 64 + cg * 4 + 3], red[0][cg * 4 + 3]);
        }
        if (tid == 0) atomicAdd(&gcnt[g], rend - rstart);
        rstart = rend;
        __syncthreads();
    }
}

// ---------------- gather: quad-group (grp=lane>>4, fl=lane&15) ----------------
__global__ void gather_k(const ushort* __restrict__ g, const int* __restrict__ rs,
                         const int* __restrict__ csr, ushort* __restrict__ out) {
    int lane = threadIdx.x & 63;
    int n = blockIdx.x * 4 + (threadIdx.x >> 6);
    if (n >= N_NODES) return;
    int start = (n == 0) ? 0 : rs[n - 1];
    int end = rs[n];
    int fl = lane & 15;
    int grp = lane >> 4;
    const char* gL = (const char*)g + (fl << 3);
    float a0 = 0.f, a1 = 0.f, a2 = 0.f, a3 = 0.f;
    float b0 = 0.f, b1 = 0.f, b2 = 0.f, b3 = 0.f;
    for (int j0 = start; j0 < end; j0 += 64) {
        int cnt = min(64, end - j0);
        int myoff = (lane < cnt) ? csr[j0 + lane] : 0;
        int j = 0;
        for (; j + 8 <= cnt; j += 8) {
            int s0 = __shfl(myoff, j + grp, 64);
            int s1 = __shfl(myoff, j + 4 + grp, 64);
            uint2 u0 = *(const uint2*)(gL + s0);
            uint2 u1 = *(const uint2*)(gL + s1);
            a0 += __uint_as_float(u0.x << 16);
            a1 += __uint_as_float(u0.x & 0xffff0000u);
            a2 += __uint_as_float(u0.y << 16);
            a3 += __uint_as_float(u0.y & 0xffff0000u);
            b0 += __uint_as_float(u1.x << 16);
            b1 += __uint_as_float(u1.x & 0xffff0000u);
            b2 += __uint_as_float(u1.y << 16);
            b3 += __uint_as_float(u1.y & 0xffff0000u);
        }
        for (; j < cnt; j += 4) {
            int idx = j + grp;
            int s = __shfl(myoff, (idx < cnt) ? idx : (cnt - 1), 64);
            uint2 u = *(const uint2*)(gL + s);
            if (idx < cnt) {
                a0 += __uint_as_float(u.x << 16);
                a1 += __uint_as_float(u.x & 0xffff0000u);
                a2 += __uint_as_float(u.y << 16);
                a3 += __uint_as_float(u.y & 0xffff0000u);
            }
        }
    }
    float v0 = a0 + b0, v1 = a1 + b1, v2 = a2 + b2, v3 = a3 + b3;
    v0 += __shfl_xor(v0, 16, 64); v0 += __shfl_xor(v0, 32, 64);
    v1 += __shfl_xor(v1, 16, 64); v1 += __shfl_xor(v1, 32, 64);
    v2 += __shfl_xor(v2, 16, 64); v2 += __shfl_xor(v2, 32, 64);
    v3 += __shfl_xor(v3, 16, 64); v3 += __shfl_xor(v3, 32, 64);
    if (grp == 0) {
        int d = end - start;
        float r0, r1, r2, r3;
        if (d > 0) {
            float inv = 1.0f / (float)d;
            r0 = v0 * inv; r1 = v1 * inv; r2 = v2 * inv; r3 = v3 * inv;
        } else {
            uint2 u = *(const uint2*)((const char*)g + (size_t)n * 128 + (fl << 3));
            r0 = __uint_as_float(u.x << 16);
            r1 = __uint_as_float(u.x & 0xffff0000u);
            r2 = __uint_as_float(u.y << 16);
            r3 = __uint_as_float(u.y & 0xffff0000u);
        }
        ushort4 o;
        o.x = f2bf(fmaxf(r0, 0.f)); o.y = f2bf(fmaxf(r1, 0.f));
        o.z = f2bf(fmaxf(r2, 0.f)); o.w = f2bf(fmaxf(r3, 0.f));
        *(ushort4*)((char*)out + (size_t)n * 128 + (fl << 3)) = o;
    }
}

// ---------------- gather2 variant: NO relu (t = mean-agg(h1) or h1[n]) ----------------
__global__ void gather_noact_k(const ushort* __restrict__ g, const int* __restrict__ rs,
                               const int* __restrict__ csr, ushort* __restrict__ out) {
    int lane = threadIdx.x & 63;
    int n = blockIdx.x * 4 + (threadIdx.x >> 6);
    if (n >= N_NODES) return;
    int start = (n == 0) ? 0 : rs[n - 1];
    int end = rs[n];
    int fl = lane & 15;
    int grp = lane >> 4;
    const char* gL = (const char*)g + (fl << 3);
    float a0 = 0.f, a1 = 0.f, a2 = 0.f, a3 = 0.f;
    float b0 = 0.f, b1 = 0.f, b2 = 0.f, b3 = 0.f;
    for (int j0 = start; j0 < end; j0 += 64) {
        int cnt = min(64, end - j0);
        int myoff = (lane < cnt) ? csr[j0 + lane] : 0;
        int j = 0;
        for (; j + 8 <= cnt; j += 8) {
            int s0 = __shfl(myoff, j + grp, 64);
            int s1 = __shfl(myoff, j + 4 + grp, 64);
            uint2 u0 = *(const uint2*)(gL + s0);
            uint2 u1 = *(const uint2*)(gL + s1);
            a0 += __uint_as_float(u0.x << 16);
            a1 += __uint_as_float(u0.x & 0xffff0000u);
            a2 += __uint_as_float(u0.y << 16);
            a3 += __uint_as_float(u0.y & 0xffff0000u);
            b0 += __uint_as_float(u1.x << 16);
            b1 += __uint_as_float(u1.x & 0xffff0000u);
            b2 += __uint_as_float(u1.y << 16);
            b3 += __uint_as_float(u1.y & 0xffff0000u);
        }
        for (; j < cnt; j += 4) {
            int idx = j + grp;
            int s = __shfl(myoff, (idx < cnt) ? idx : (cnt - 1), 64);
            uint2 u = *(const uint2*)(gL + s);
            if (idx < cnt) {
                a0 += __uint_as_float(u.x << 16);
                a1 += __uint_as_float(u.x & 0xffff0000u);
                a2 += __uint_as_float(u.y << 16);
                a3 += __uint_as_float(u.y & 0xffff0000u);
            }
        }
    }
    float v0 = a0 + b0, v1 = a1 + b1, v2 = a2 + b2, v3 = a3 + b3;
    v0 += __shfl_xor(v0, 16, 64); v0 += __shfl_xor(v0, 32, 64);
    v1 += __shfl_xor(v1, 16, 64); v1 += __shfl_xor(v1, 32, 64);
    v2 += __shfl_xor(v2, 16, 64); v2 += __shfl_xor(v2, 32, 64);
    v3 += __shfl_xor(v3, 16, 64); v3 += __shfl_xor(v3, 32, 64);
    if (grp == 0) {
        int d = end - start;
        float r0, r1, r2, r3;
        if (d > 0) {
            float inv = 1.0f / (float)d;
            r0 = v0 * inv; r1 = v1 * inv; r2 = v2 * inv; r3 = v3 * inv;
        } else {
            uint2 u = *(const uint2*)((const char*)g + (size_t)n * 128 + (fl << 3));
            r0 = __uint_as_float(u.x << 16);
            r1 = __uint_as_float(u.x & 0xffff0000u);
            r2 = __uint_as_float(u.y << 16);
            r3 = __uint_as_float(u.y & 0xffff0000u);
        }
        ushort4 o;
        o.x = f2bf(r0); o.y = f2bf(r1); o.z = f2bf(r2); o.w = f2bf(r3);
        *(ushort4*)((char*)out + (size_t)n * 128 + (fl << 3)) = o;
    }
}

// ---------------- FC head + sigmoid (weights staged in LDS) ----------------
__global__ void head_k(const float* __restrict__ gsum, const int* __restrict__ gcnt,
                       const float* __restrict__ fc1w, const float* __restrict__ fc1b,
                       const float* __restrict__ fc2w, const float* __restrict__ fc2b,
                       float* __restrict__ out) {
    __shared__ float w1[H * 32];
    __shared__ float w2[32], bb1[32];
    int b = threadIdx.x;
    for (int i = b; i < H * 32; i += 64) w1[i] = fc1w[i];
    if (b < 32) { w2[b] = fc2w[b]; bb1[b] = fc1b[b]; }
    __syncthreads();
    if (b >= N_GRAPHS_C) return;
    float hg[H];
    float inv = 1.0f / fmaxf((float)gcnt[b], 1.0f);
    for (int k = 0; k < H; k++) hg[k] = gsum[b * H + k] * inv;
    float z = fc2b[0];
    for (int j = 0; j < 32; j++) {
        float t = bb1[j];
        for (int k = 0; k < H; k++) t += hg[k] * w1[k * 32 + j];
        z += t * w2[j];
    }
    out[b] = 1.0f / (1.0f + expf(-z));
}

extern "C" void kernel_launch(void* const* d_in, const int* in_sizes, int n_in,
                              void* d_out, int out_size, void* d_ws, size_t ws_size,
                              hipStream_t stream) {
    const float* x        = (const float*)d_in[0];
    const int*   edge_src = (const int*)d_in[1];
    const int*   edge_dst = (const int*)d_in[2];
    const int*   gid      = (const int*)d_in[3];
    const float* bn_gamma = (const float*)d_in[5];
    const float* bn_beta  = (const float*)d_in[6];
    const float* W1       = (const float*)d_in[7];
    const float* b1       = (const float*)d_in[8];
    const float* W2       = (const float*)d_in[9];
    const float* b2       = (const float*)d_in[10];
    const float* fc1w     = (const float*)d_in[11];
    const float* fc1b     = (const float*)d_in[12];
    const float* fc2w     = (const float*)d_in[13];
    const float* fc2b     = (const float*)d_in[14];
    float* out = (float*)d_out;

    // ---- workspace layout ----
    char* ws = (char*)d_ws;
    size_t off = 0;
    auto alloc = [&](size_t bytes) { void* p = ws + off; off += (bytes + 255) & ~(size_t)255; return p; };
    // zero-region: bnsum[86] bnsq[86] bcnt[391] gsum[4096] gcnt[64]  (one memset)
    const size_t ZW = IN_F + IN_F + N_BKT + N_GRAPHS_C * H + N_GRAPHS_C;
    float* zreg  = (float*)alloc(ZW * sizeof(float));
    float* bnsum = zreg;
    float* bnsq  = bnsum + IN_F;
    int*   bcnt  = (int*)(bnsq + IN_F);
    float* gsum  = (float*)(bcnt + N_BKT);
    int*   gcnt  = (int*)(gsum + N_GRAPHS_C * H);
    float* W1p     = (float*)alloc(IN_F * H * sizeof(float));
    float* c1      = (float*)alloc(H * sizeof(float));
    int*   bstart  = (int*)alloc((N_BKT + 1) * sizeof(int));
    int*   gcursor = (int*)alloc(N_BKT * sizeof(int));
    int*   rs      = (int*)alloc(N_NODES * sizeof(int));
    int*   csr     = (int*)alloc((size_t)N_EDGES * sizeof(int));
    ushort* gbuf   = (ushort*)alloc((size_t)N_NODES * H * sizeof(ushort));  // bf16 g1, then t (12.8 MB)
    ushort* h1     = (ushort*)alloc((size_t)N_NODES * H * sizeof(ushort));  // bf16 h1 (12.8 MB)
    // ebkt (6.4 MB packed) aliases gbuf: consumed by bucket_fill_k BEFORE gemm writes gbuf.
    unsigned* ebkt = (unsigned*)gbuf;

    hipMemsetAsync(zreg, 0, ZW * sizeof(float), stream);

    // ---- fused BN stats + bucket counts ----
    bn_count_k<<<BC_GRID, 256, 0, stream>>>(x, edge_dst, bnsum, bnsq, bcnt);
    // ---- fused bucket scan + BN fold ----
    scanprep_k<<<1, 512, 0, stream>>>(bcnt, bstart, gcursor, bnsum, bnsq,
                                      bn_gamma, bn_beta, W1, b1, W1p, c1);
    // ---- CSR build ----
    bucket_scatter_k<<<SC_GRID, 256, 0, stream>>>(edge_src, edge_dst, gcursor, ebkt);
    bucket_fill_k<<<N_BKT, 256, 0, stream>>>(ebkt, bstart, rs, csr);

    // ---- layer 1: g1 = x @ W1p + c1 ; h1 = relu(mean-agg(g1)) ----
    gemm_f32_k<<<(N_NODES + 63) / 64, 256, 0, stream>>>(x, W1p, c1, gbuf, N_NODES);
    gather_k<<<(N_NODES + 3) / 4, 256, 0, stream>>>(gbuf, rs, csr, h1);

    // ---- layer 2 (aggregate-then-transform): t = mean-agg(h1); pool relu(t@W2+b2) ----
    gather_noact_k<<<(N_NODES + 3) / 4, 256, 0, stream>>>(h1, rs, csr, gbuf);
    gemm2pool_k<<<(N_NODES + 63) / 64, 256, 0, stream>>>(gbuf, W2, b2, gid, gsum, gcnt, N_NODES);

    // ---- head ----
    head_k<<<1, 64, 0, stream>>>(gsum, gcnt, fc1w, fc1b, fc2w, fc2b, out);
}

// Round 13
// 354.653 us; speedup vs baseline: 1.3429x; 1.0158x over previous
//
#include <hip/hip_runtime.h>

#define N_NODES 100000
#define N_EDGES 1600000
#define N_GRAPHS_C 64
#define IN_F 86
#define H 64
#define N_BKT 391            // ceil(100000/256), bucket = dst >> 8
#define SC_EPT 8             // edges per thread in bucket passes
#define SC_TILE 2048         // 256 threads * 8
#define SC_GRID 782          // ceil(1.6M / 2048)
#define BC_GRID 1024         // bn+count grid (>= SC_GRID); 4096 waves
typedef unsigned short ushort;

__device__ inline float bf2f(ushort u) { return __uint_as_float(((unsigned)u) << 16); }
__device__ inline ushort f2bf(float f) {
    unsigned x = __float_as_uint(f);
    return (ushort)((x + 0x7fffu + ((x >> 16) & 1u)) >> 16);  // RNE
}

// ---------------- fused: BN stats + per-bucket edge counts ----------------
__global__ void bn_count_k(const float* __restrict__ x, const int* __restrict__ dst,
                           float* __restrict__ bnsum, float* __restrict__ bnsq,
                           int* __restrict__ bcnt) {
    __shared__ float s1[IN_F], s2[IN_F];
    __shared__ int hist[N_BKT];
    int tid = threadIdx.x;
    if (tid < IN_F) { s1[tid] = 0.f; s2[tid] = 0.f; }
    for (int i = tid; i < N_BKT; i += 256) hist[i] = 0;
    __syncthreads();
    if (blockIdx.x < SC_GRID) {
        int e0 = blockIdx.x * SC_TILE;
#pragma unroll
        for (int i = 0; i < SC_EPT; i++) {
            int e = e0 + i * 256 + tid;
            if (e < N_EDGES) atomicAdd(&hist[dst[e] >> 8], 1);
        }
    }
    const int NWAVE = BC_GRID * 4;
    const int RPW = (N_NODES + NWAVE - 1) / NWAVE;   // 25
    int lane = tid & 63;
    int w = blockIdx.x * 4 + (tid >> 6);
    int r0 = w * RPW;
    int r1 = min(r0 + RPW, N_NODES);
    float sum0 = 0.f, sq0 = 0.f, sum1 = 0.f, sq1 = 0.f;
#pragma unroll 4
    for (int r = r0; r < r1; r++) {
        const float* base = x + (size_t)r * IN_F;
        float v0 = base[lane];
        float v1 = (lane < IN_F - 64) ? base[64 + lane] : 0.f;
        sum0 += v0; sq0 += v0 * v0;
        sum1 += v1; sq1 += v1 * v1;
    }
    atomicAdd(&s1[lane], sum0);
    atomicAdd(&s2[lane], sq0);
    if (lane < IN_F - 64) {
        atomicAdd(&s1[64 + lane], sum1);
        atomicAdd(&s2[64 + lane], sq1);
    }
    __syncthreads();
    if (tid < IN_F) {
        atomicAdd(&bnsum[tid], s1[tid]);
        atomicAdd(&bnsq[tid], s2[tid]);
    }
    if (blockIdx.x < SC_GRID)
        for (int i = tid; i < N_BKT; i += 256) atomicAdd(&bcnt[i], hist[i]);
}

// ---------------- fused: bucket scan + BN-fold prep ----------------
__global__ void scanprep_k(const int* __restrict__ bcnt, int* __restrict__ bstart,
                           int* __restrict__ gcursor,
                           const float* __restrict__ bnsum, const float* __restrict__ bnsq,
                           const float* __restrict__ gamma, const float* __restrict__ beta,
                           const float* __restrict__ W1, const float* __restrict__ b1,
                           float* __restrict__ W1p, float* __restrict__ c1) {
    __shared__ int tmp[512];
    __shared__ float scale[IN_F], shift[IN_F];
    int t = threadIdx.x;
    int v = (t < N_BKT) ? bcnt[t] : 0;
    tmp[t] = v;
    __syncthreads();
    for (int off = 1; off < 512; off <<= 1) {
        int a = (t >= off) ? tmp[t - off] : 0;
        __syncthreads();
        tmp[t] += a;
        __syncthreads();
    }
    if (t < N_BKT) { bstart[t] = tmp[t] - v; gcursor[t] = tmp[t] - v; }
    if (t == N_BKT - 1) bstart[N_BKT] = tmp[t];
    if (t < IN_F) {
        float mean = bnsum[t] * (1.0f / N_NODES);
        float var  = bnsq[t] * (1.0f / N_NODES) - mean * mean;
        float sc = gamma[t] * rsqrtf(var + 1e-5f);
        scale[t] = sc;
        shift[t] = beta[t] - mean * sc;
    }
    __syncthreads();
    for (int idx = t; idx < IN_F * H; idx += 512) W1p[idx] = scale[idx / H] * W1[idx];
    if (t < H) {
        float acc = b1[t];
        for (int i = 0; i < IN_F; i++) acc += shift[i] * W1[i * H + t];
        c1[t] = acc;
    }
}

// ---------------- CSR pass 1: partition edges (packed (src<<8)|dstLow) ----------------
__global__ void bucket_scatter_k(const int* __restrict__ src, const int* __restrict__ dst,
                                 int* __restrict__ gcursor, unsigned* __restrict__ ebkt) {
    __shared__ int hist[N_BKT];
    __shared__ int base[N_BKT];
    int tid = threadIdx.x;
    for (int i = tid; i < N_BKT; i += 256) hist[i] = 0;
    __syncthreads();
    int e0 = blockIdx.x * SC_TILE;
    unsigned pk[SC_EPT];
    int bk[SC_EPT], lo[SC_EPT];
#pragma unroll
    for (int i = 0; i < SC_EPT; i++) {
        int e = e0 + i * 256 + tid;
        if (e < N_EDGES) {
            int d = dst[e];
            pk[i] = ((unsigned)src[e] << 8) | (unsigned)(d & 255);
            bk[i] = d >> 8;
            lo[i] = atomicAdd(&hist[bk[i]], 1);
        }
    }
    __syncthreads();
    for (int i = tid; i < N_BKT; i += 256) base[i] = atomicAdd(&gcursor[i], hist[i]);
    __syncthreads();
#pragma unroll
    for (int i = 0; i < SC_EPT; i++) {
        int e = e0 + i * 256 + tid;
        if (e < N_EDGES) ebkt[base[bk[i]] + lo[i]] = pk[i];
    }
}

// ---------------- CSR pass 2: per-bucket degree+scan+fill ----------------
// rs[n] = INCLUSIVE end of node n's csr row. csr entries are BYTE offsets (src*128).
__global__ void bucket_fill_k(const unsigned* __restrict__ ebkt, const int* __restrict__ bstart,
                              int* __restrict__ rs, int* __restrict__ csr) {
    __shared__ int deg[256];
    __shared__ int scn[256];
    __shared__ int cur[256];
    int b = blockIdx.x;
    int tid = threadIdx.x;
    int e0 = bstart[b], e1 = bstart[b + 1];
    deg[tid] = 0;
    __syncthreads();
    for (int e = e0 + tid; e < e1; e += 256) atomicAdd(&deg[ebkt[e] & 255u], 1);
    __syncthreads();
    scn[tid] = deg[tid];
    __syncthreads();
    for (int off = 1; off < 256; off <<= 1) {
        int a = (tid >= off) ? scn[tid - off] : 0;
        __syncthreads();
        scn[tid] += a;
        __syncthreads();
    }
    int node = (b << 8) + tid;
    if (node < N_NODES) rs[node] = e0 + scn[tid];
    cur[tid] = e0 + scn[tid] - deg[tid];
    __syncthreads();
    for (int e = e0 + tid; e < e1; e += 256) {
        unsigned p = ebkt[e];
        int pos = atomicAdd(&cur[p & 255u], 1);
        csr[pos] = (int)((p & ~255u) >> 1);   // src*128 byte offset
    }
}

// ---------------- quad-group aggregate core (csr = byte offsets) ----------------
// All lanes participate; returns the full 4-feature sum (per fl group) in all lanes.
__device__ inline float4 agg_quad(const char* __restrict__ gL, const int* __restrict__ csr,
                                  int start, int end, int lane, int grp) {
    float a0 = 0.f, a1 = 0.f, a2 = 0.f, a3 = 0.f;
    float b0 = 0.f, b1 = 0.f, b2 = 0.f, b3 = 0.f;
    for (int j0 = start; j0 < end; j0 += 64) {
        int cnt = min(64, end - j0);
        int myoff = (lane < cnt) ? csr[j0 + lane] : 0;
        int j = 0;
        for (; j + 8 <= cnt; j += 8) {
            int s0 = __shfl(myoff, j + grp, 64);
            int s1 = __shfl(myoff, j + 4 + grp, 64);
            uint2 u0 = *(const uint2*)(gL + s0);
            uint2 u1 = *(const uint2*)(gL + s1);
            a0 += __uint_as_float(u0.x << 16);
            a1 += __uint_as_float(u0.x & 0xffff0000u);
            a2 += __uint_as_float(u0.y << 16);
            a3 += __uint_as_float(u0.y & 0xffff0000u);
            b0 += __uint_as_float(u1.x << 16);
            b1 += __uint_as_float(u1.x & 0xffff0000u);
            b2 += __uint_as_float(u1.y << 16);
            b3 += __uint_as_float(u1.y & 0xffff0000u);
        }
        for (; j < cnt; j += 4) {
            int idx = j + grp;
            int s = __shfl(myoff, (idx < cnt) ? idx : (cnt - 1), 64);
            uint2 u = *(const uint2*)(gL + s);
            if (idx < cnt) {
                a0 += __uint_as_float(u.x << 16);
                a1 += __uint_as_float(u.x & 0xffff0000u);
                a2 += __uint_as_float(u.y << 16);
                a3 += __uint_as_float(u.y & 0xffff0000u);
            }
        }
    }
    float v0 = a0 + b0, v1 = a1 + b1, v2 = a2 + b2, v3 = a3 + b3;
    v0 += __shfl_xor(v0, 16, 64); v0 += __shfl_xor(v0, 32, 64);
    v1 += __shfl_xor(v1, 16, 64); v1 += __shfl_xor(v1, 32, 64);
    v2 += __shfl_xor(v2, 16, 64); v2 += __shfl_xor(v2, 32, 64);
    v3 += __shfl_xor(v3, 16, 64); v3 += __shfl_xor(v3, 32, 64);
    return make_float4(v0, v1, v2, v3);
}

// ---------------- GEMM (f32 in, K=86): Ybf16 = X @ W + bias ----------------
// bf16 X and W tiles in LDS (23.4 KB total -> 6 blocks/CU).
__global__ __launch_bounds__(256) void gemm_f32_k(const float* __restrict__ X,
                                                  const float* __restrict__ W,
                                                  const float* __restrict__ bias,
                                                  ushort* __restrict__ Y, int N) {
    const int K = IN_F;
    __shared__ __align__(16) ushort Xt[IN_F][72];
    __shared__ __align__(16) ushort Wl[IN_F][64];
    int tid = threadIdx.x;
    int row0 = blockIdx.x * 64;
    for (int i = tid; i < K * 64; i += 256) Wl[i / 64][i % 64] = f2bf(W[i]);
    for (int i = tid; i < 64 * K; i += 256) {
        int r = i / K, c = i % K;
        Xt[c][r] = (row0 + r < N) ? f2bf(X[(size_t)(row0 + r) * K + c]) : (ushort)0;
    }
    __syncthreads();
    int cg = tid & 15, rg = tid >> 4;
    float4 b4 = *(const float4*)&bias[cg * 4];
    float acc[4][4];
    for (int i = 0; i < 4; i++) { acc[i][0] = b4.x; acc[i][1] = b4.y; acc[i][2] = b4.z; acc[i][3] = b4.w; }
    for (int k = 0; k < K; k++) {
        ushort4 wu = *(const ushort4*)&Wl[k][cg * 4];
        ushort4 xu = *(const ushort4*)&Xt[k][rg * 4];
        float w0 = bf2f(wu.x), w1 = bf2f(wu.y), w2 = bf2f(wu.z), w3 = bf2f(wu.w);
        float x0 = bf2f(xu.x), x1 = bf2f(xu.y), x2 = bf2f(xu.z), x3 = bf2f(xu.w);
        acc[0][0] += x0 * w0; acc[0][1] += x0 * w1; acc[0][2] += x0 * w2; acc[0][3] += x0 * w3;
        acc[1][0] += x1 * w0; acc[1][1] += x1 * w1; acc[1][2] += x1 * w2; acc[1][3] += x1 * w3;
        acc[2][0] += x2 * w0; acc[2][1] += x2 * w1; acc[2][2] += x2 * w2; acc[2][3] += x2 * w3;
        acc[3][0] += x3 * w0; acc[3][1] += x3 * w1; acc[3][2] += x3 * w2; acc[3][3] += x3 * w3;
    }
    for (int i = 0; i < 4; i++) {
        int gr = row0 + rg * 4 + i;
        if (gr < N) {
            ushort4 o;
            o.x = f2bf(acc[i][0]); o.y = f2bf(acc[i][1]);
            o.z = f2bf(acc[i][2]); o.w = f2bf(acc[i][3]);
            *(ushort4*)&Y[(size_t)gr * 64 + cg * 4] = o;
        }
    }
}

// ---------------- gather: h1[n] = relu(mean-agg(g1) or g1[n]) -> bf16 ----------------
__global__ void gather_k(const ushort* __restrict__ g, const int* __restrict__ rs,
                         const int* __restrict__ csr, ushort* __restrict__ out) {
    int lane = threadIdx.x & 63;
    int n = blockIdx.x * 4 + (threadIdx.x >> 6);
    if (n >= N_NODES) return;
    int start = (n == 0) ? 0 : rs[n - 1];
    int end = rs[n];
    int fl = lane & 15;
    int grp = lane >> 4;
    float4 v = agg_quad((const char*)g + (fl << 3), csr, start, end, lane, grp);
    if (grp == 0) {
        int d = end - start;
        float r0, r1, r2, r3;
        if (d > 0) {
            float inv = 1.0f / (float)d;
            r0 = v.x * inv; r1 = v.y * inv; r2 = v.z * inv; r3 = v.w * inv;
        } else {
            uint2 u = *(const uint2*)((const char*)g + (size_t)n * 128 + (fl << 3));
            r0 = __uint_as_float(u.x << 16);
            r1 = __uint_as_float(u.x & 0xffff0000u);
            r2 = __uint_as_float(u.y << 16);
            r3 = __uint_as_float(u.y & 0xffff0000u);
        }
        ushort4 o;
        o.x = f2bf(fmaxf(r0, 0.f)); o.y = f2bf(fmaxf(r1, 0.f));
        o.z = f2bf(fmaxf(r2, 0.f)); o.w = f2bf(fmaxf(r3, 0.f));
        *(ushort4*)((char*)out + (size_t)n * 128 + (fl << 3)) = o;
    }
}

// ---------------- fused aggregate + GEMM2 + pool ----------------
// Per block: 4 waves aggregate t-rows (no relu) for 64 nodes straight into LDS Xt,
// then gemm relu(t@W2+b2) + per-graph run pooling (sorted gids).
__global__ __launch_bounds__(256) void agg_gemm2pool_k(const ushort* __restrict__ h1,
                                                       const int* __restrict__ rs,
                                                       const int* __restrict__ csr,
                                                       const float* __restrict__ W,
                                                       const float* __restrict__ bias,
                                                       const int* __restrict__ gid,
                                                       float* __restrict__ gsum,
                                                       int* __restrict__ gcnt, int N) {
    const int K = H;
    __shared__ __align__(16) ushort Xt[H][72];
    __shared__ __align__(16) ushort Wl[H][64];
    __shared__ int gl[64];
    __shared__ __align__(16) float red[16][64];
    int tid = threadIdx.x;
    int row0 = blockIdx.x * 64;
    for (int i = tid; i < K * 64; i += 256) Wl[i / 64][i % 64] = f2bf(W[i]);
    if (tid < 64) gl[tid] = (row0 + tid < N) ? gid[row0 + tid] : -1;
    // ---- aggregation phase: wave wv owns rows [16wv, 16wv+16) ----
    int lane = tid & 63, wv = tid >> 6;
    int fl = lane & 15, grp = lane >> 4;
    const char* gL = (const char*)h1 + (fl << 3);
    for (int i = 0; i < 16; i++) {
        int r = wv * 16 + i;
        int n = row0 + r;
        if (n < N) {
            int start = (n == 0) ? 0 : rs[n - 1];
            int end = rs[n];
            float4 v = agg_quad(gL, csr, start, end, lane, grp);
            if (grp == 0) {
                int d = end - start;
                float r0, r1, r2, r3;
                if (d > 0) {
                    float inv = 1.0f / (float)d;
                    r0 = v.x * inv; r1 = v.y * inv; r2 = v.z * inv; r3 = v.w * inv;
                } else {
                    uint2 u = *(const uint2*)((const char*)h1 + (size_t)n * 128 + (fl << 3));
                    r0 = __uint_as_float(u.x << 16);
                    r1 = __uint_as_float(u.x & 0xffff0000u);
                    r2 = __uint_as_float(u.y << 16);
                    r3 = __uint_as_float(u.y & 0xffff0000u);
                }
                Xt[fl * 4 + 0][r] = f2bf(r0);
                Xt[fl * 4 + 1][r] = f2bf(r1);
                Xt[fl * 4 + 2][r] = f2bf(r2);
                Xt[fl * 4 + 3][r] = f2bf(r3);
            }
        } else if (grp == 0) {
            Xt[fl * 4 + 0][r] = 0; Xt[fl * 4 + 1][r] = 0;
            Xt[fl * 4 + 2][r] = 0; Xt[fl * 4 + 3][r] = 0;
        }
    }
    __syncthreads();
    // ---- gemm phase ----
    int cg = tid & 15, rg = tid >> 4;
    float4 b4 = *(const float4*)&bias[cg * 4];
    float acc[4][4];
    for (int i = 0; i < 4; i++) { acc[i][0] = b4.x; acc[i][1] = b4.y; acc[i][2] = b4.z; acc[i][3] = b4.w; }
    for (int k = 0; k < K; k++) {
        ushort4 wu = *(const ushort4*)&Wl[k][cg * 4];
        ushort4 xu = *(const ushort4*)&Xt[k][rg * 4];
        float w0 = bf2f(wu.x), w1 = bf2f(wu.y), w2 = bf2f(wu.z), w3 = bf2f(wu.w);
        float x0 = bf2f(xu.x), x1 = bf2f(xu.y), x2 = bf2f(xu.z), x3 = bf2f(xu.w);
        acc[0][0] += x0 * w0; acc[0][1] += x0 * w1; acc[0][2] += x0 * w2; acc[0][3] += x0 * w3;
        acc[1][0] += x1 * w0; acc[1][1] += x1 * w1; acc[1][2] += x1 * w2; acc[1][3] += x1 * w3;
        acc[2][0] += x2 * w0; acc[2][1] += x2 * w1; acc[2][2] += x2 * w2; acc[2][3] += x2 * w3;
        acc[3][0] += x3 * w0; acc[3][1] += x3 * w1; acc[3][2] += x3 * w2; acc[3][3] += x3 * w3;
    }
    for (int i = 0; i < 4; i++)
        for (int j = 0; j < 4; j++) acc[i][j] = fmaxf(acc[i][j], 0.f);
    // ---- pool runs of equal gid (sorted); uniform control flow across block ----
    int rstart = 0;
    while (rstart < 64) {
        int g = gl[rstart];
        if (g < 0) break;
        int rend = rstart + 1;
        while (rend < 64 && gl[rend] == g) rend++;
        float p0 = 0.f, p1 = 0.f, p2 = 0.f, p3 = 0.f;
#pragma unroll
        for (int i = 0; i < 4; i++) {
            int r = rg * 4 + i;
            if (r >= rstart && r < rend) { p0 += acc[i][0]; p1 += acc[i][1]; p2 += acc[i][2]; p3 += acc[i][3]; }
        }
        *(float4*)&red[rg][cg * 4] = make_float4(p0, p1, p2, p3);
        __syncthreads();
        for (int s = 8; s >= 1; s >>= 1) {
            if (rg < s) {
                float4 a = *(float4*)&red[rg][cg * 4];
                float4 b = *(float4*)&red[rg + s][cg * 4];
                *(float4*)&red[rg][cg * 4] = make_float4(a.x + b.x, a.y + b.y, a.z + b.z, a.w + b.w);
            }
            __syncthreads();
        }
        if (rg == 0) {
            atomicAdd(&gsum[g * 64 + cg * 4 + 0], red[0][cg * 4 + 0]);
            atomicAdd(&gsum[g * 64 + cg * 4 + 1], red[0][cg * 4 + 1]);
            atomicAdd(&gsum[g * 64 + cg * 4 + 2], red[0][cg * 4 + 2]);
            atomicAdd(&gsum[g * 64 + cg * 4 + 3], red[0][cg * 4 + 3]);
        }
        if (tid == 0) atomicAdd(&gcnt[g], rend - rstart);
        rstart = rend;
        __syncthreads();
    }
}

// ---------------- FC head + sigmoid (weights staged in LDS) ----------------
__global__ void head_k(const float* __restrict__ gsum, const int* __restrict__ gcnt,
                       const float* __restrict__ fc1w, const float* __restrict__ fc1b,
                       const float* __restrict__ fc2w, const float* __restrict__ fc2b,
                       float* __restrict__ out) {
    __shared__ float w1[H * 32];
    __shared__ float w2[32], bb1[32];
    int b = threadIdx.x;
    for (int i = b; i < H * 32; i += 64) w1[i] = fc1w[i];
    if (b < 32) { w2[b] = fc2w[b]; bb1[b] = fc1b[b]; }
    __syncthreads();
    if (b >= N_GRAPHS_C) return;
    float hg[H];
    float inv = 1.0f / fmaxf((float)gcnt[b], 1.0f);
    for (int k = 0; k < H; k++) hg[k] = gsum[b * H + k] * inv;
    float z = fc2b[0];
    for (int j = 0; j < 32; j++) {
        float t = bb1[j];
        for (int k = 0; k < H; k++) t += hg[k] * w1[k * 32 + j];
        z += t * w2[j];
    }
    out[b] = 1.0f / (1.0f + expf(-z));
}

extern "C" void kernel_launch(void* const* d_in, const int* in_sizes, int n_in,
                              void* d_out, int out_size, void* d_ws, size_t ws_size,
                              hipStream_t stream) {
    const float* x        = (const float*)d_in[0];
    const int*   edge_src = (const int*)d_in[1];
    const int*   edge_dst = (const int*)d_in[2];
    const int*   gid      = (const int*)d_in[3];
    const float* bn_gamma = (const float*)d_in[5];
    const float* bn_beta  = (const float*)d_in[6];
    const float* W1       = (const float*)d_in[7];
    const float* b1       = (const float*)d_in[8];
    const float* W2       = (const float*)d_in[9];
    const float* b2       = (const float*)d_in[10];
    const float* fc1w     = (const float*)d_in[11];
    const float* fc1b     = (const float*)d_in[12];
    const float* fc2w     = (const float*)d_in[13];
    const float* fc2b     = (const float*)d_in[14];
    float* out = (float*)d_out;

    // ---- workspace layout ----
    char* ws = (char*)d_ws;
    size_t off = 0;
    auto alloc = [&](size_t bytes) { void* p = ws + off; off += (bytes + 255) & ~(size_t)255; return p; };
    // zero-region: bnsum[86] bnsq[86] bcnt[391] gsum[4096] gcnt[64]  (one memset)
    const size_t ZW = IN_F + IN_F + N_BKT + N_GRAPHS_C * H + N_GRAPHS_C;
    float* zreg  = (float*)alloc(ZW * sizeof(float));
    float* bnsum = zreg;
    float* bnsq  = bnsum + IN_F;
    int*   bcnt  = (int*)(bnsq + IN_F);
    float* gsum  = (float*)(bcnt + N_BKT);
    int*   gcnt  = (int*)(gsum + N_GRAPHS_C * H);
    float* W1p     = (float*)alloc(IN_F * H * sizeof(float));
    float* c1      = (float*)alloc(H * sizeof(float));
    int*   bstart  = (int*)alloc((N_BKT + 1) * sizeof(int));
    int*   gcursor = (int*)alloc(N_BKT * sizeof(int));
    int*   rs      = (int*)alloc(N_NODES * sizeof(int));
    int*   csr     = (int*)alloc((size_t)N_EDGES * sizeof(int));
    ushort* gbuf   = (ushort*)alloc((size_t)N_NODES * H * sizeof(ushort));  // bf16 g1 (12.8 MB)
    ushort* h1     = (ushort*)alloc((size_t)N_NODES * H * sizeof(ushort));  // bf16 h1 (12.8 MB)
    // ebkt (6.4 MB packed) aliases gbuf: consumed by bucket_fill_k BEFORE gemm writes gbuf.
    unsigned* ebkt = (unsigned*)gbuf;

    hipMemsetAsync(zreg, 0, ZW * sizeof(float), stream);

    // ---- fused BN stats + bucket counts ----
    bn_count_k<<<BC_GRID, 256, 0, stream>>>(x, edge_dst, bnsum, bnsq, bcnt);
    // ---- fused bucket scan + BN fold ----
    scanprep_k<<<1, 512, 0, stream>>>(bcnt, bstart, gcursor, bnsum, bnsq,
                                      bn_gamma, bn_beta, W1, b1, W1p, c1);
    // ---- CSR build ----
    bucket_scatter_k<<<SC_GRID, 256, 0, stream>>>(edge_src, edge_dst, gcursor, ebkt);
    bucket_fill_k<<<N_BKT, 256, 0, stream>>>(ebkt, bstart, rs, csr);

    // ---- layer 1: g1 = x @ W1p + c1 ; h1 = relu(mean-agg(g1)) ----
    gemm_f32_k<<<(N_NODES + 63) / 64, 256, 0, stream>>>(x, W1p, c1, gbuf, N_NODES);
    gather_k<<<(N_NODES + 3) / 4, 256, 0, stream>>>(gbuf, rs, csr, h1);

    // ---- layer 2 fused: t = mean-agg(h1) (in LDS); pool relu(t@W2+b2) ----
    agg_gemm2pool_k<<<(N_NODES + 63) / 64, 256, 0, stream>>>(h1, rs, csr, W2, b2,
                                                             gid, gsum, gcnt, N_NODES);

    // ---- head ----
    head_k<<<1, 64, 0, stream>>>(gsum, gcnt, fc1w, fc1b, fc2w, fc2b, out);
}